// Round 6
// baseline (678.888 us; speedup 1.0000x reference)
//
#include <hip/hip_runtime.h>
#include <hip/hip_bf16.h>

// VGAE forward, MI355X. Gather-based GCN; bf16 storage for all gathered operands.
// CSR build via two-level binned counting sort. Random-gather kernels are
// dimension-sliced so the hot array slice (3.2MB) is per-XCD-L2 resident.
constexpr int N_ = 50000;
constexpr int E_ = 1600000;
constexpr int D_ = 128;   // embedding_dim == hidden_dim
constexpr int O_ = 64;    // out_embedding_dim
constexpr int NNZ_ = 16;
constexpr int V_ = 100000;
constexpr int NBIN_ = (N_ + 255) / 256;   // 196 coarse bins (dst>>8)

static __device__ __forceinline__ unsigned short f2bf(float f) {
    __hip_bfloat16 h = __float2bfloat16(f);
    return __builtin_bit_cast(unsigned short, h);
}
static __device__ __forceinline__ float blo(unsigned int u) { return __uint_as_float(u << 16); }
static __device__ __forceinline__ float bhi(unsigned int u) { return __uint_as_float(u & 0xffff0000u); }
static __device__ __forceinline__ float4 fma4(float s, float4 a, float4 b) {
    return make_float4(fmaf(s, a.x, b.x), fmaf(s, a.y, b.y),
                       fmaf(s, a.z, b.z), fmaf(s, a.w, b.w));
}

// ---------------------------------------------------------------------------
// 0. Convert fp32 emb table [V][128] -> bf16 (packed u32 pairs).
// ---------------------------------------------------------------------------
__global__ __launch_bounds__(256) void k_cvt(const float* __restrict__ emb,
                                             unsigned int* __restrict__ emb_bf) {
    int t = blockIdx.x * blockDim.x + threadIdx.x;
    if (t >= V_ * D_ / 8) return;
    float4 a = ((const float4*)emb)[t * 2];
    float4 b = ((const float4*)emb)[t * 2 + 1];
    uint4 o;
    o.x = (unsigned int)f2bf(a.x) | ((unsigned int)f2bf(a.y) << 16);
    o.y = (unsigned int)f2bf(a.z) | ((unsigned int)f2bf(a.w) << 16);
    o.z = (unsigned int)f2bf(b.x) | ((unsigned int)f2bf(b.y) << 16);
    o.w = (unsigned int)f2bf(b.z) | ((unsigned int)f2bf(b.w) << 16);
    ((uint4*)emb_bf)[t] = o;
}

// ---------------------------------------------------------------------------
// 1. EmbeddingBag(sum) + L2 normalize from bf16 table. One wave per node.
// ---------------------------------------------------------------------------
__global__ __launch_bounds__(256) void k_embed(const int* __restrict__ fi,
                                               const float* __restrict__ fw,
                                               const unsigned int* __restrict__ emb_bf,
                                               unsigned int* __restrict__ x) {
    int n = blockIdx.x * 4 + (threadIdx.x >> 6);
    if (n >= N_) return;
    int lane = threadIdx.x & 63;
    float a0 = 0.f, a1 = 0.f;
    int base = n * NNZ_;
#pragma unroll
    for (int j = 0; j < NNZ_; ++j) {
        int idx  = fi[base + j];
        float w  = fw[base + j];
        unsigned int r = emb_bf[(size_t)idx * 64 + lane];
        a0 = fmaf(w, blo(r), a0);
        a1 = fmaf(w, bhi(r), a1);
    }
    float ss = a0 * a0 + a1 * a1;
#pragma unroll
    for (int o = 32; o; o >>= 1) ss += __shfl_xor(ss, o);
    float sc = 1.0f / fmaxf(sqrtf(ss), 1e-12f);
    x[(size_t)n * 64 + lane] =
        (unsigned int)f2bf(a0 * sc) | ((unsigned int)f2bf(a1 * sc) << 16);
}

// ---------------------------------------------------------------------------
// 2. In-degree histogram + normalization factors
// ---------------------------------------------------------------------------
__global__ __launch_bounds__(256) void k_degcnt(const int* __restrict__ dst,
                                                int* __restrict__ cnt) {
    int e = blockIdx.x * blockDim.x + threadIdx.x;
    if (e < E_) atomicAdd(&cnt[dst[e]], 1);
}

__global__ __launch_bounds__(256) void k_degnorm(const int* __restrict__ cnt,
                                                 float* __restrict__ disq,
                                                 float* __restrict__ dinv) {
    int n = blockIdx.x * blockDim.x + threadIdx.x;
    if (n < N_) {
        float deg = 1.0f + (float)cnt[n];
        disq[n] = rsqrtf(deg);
        dinv[n] = 1.0f / deg;
    }
}

// ---------------------------------------------------------------------------
// 3a. Per-coarse-bin edge-count: bsum[bin] = sum of cnt over its 256 nodes.
// ---------------------------------------------------------------------------
__global__ __launch_bounds__(256) void k_bsum(const int* __restrict__ cnt,
                                              int* __restrict__ bsum) {
    int t = threadIdx.x, n = (blockIdx.x << 8) + t;
    int v = (n < N_) ? cnt[n] : 0;
#pragma unroll
    for (int o = 32; o; o >>= 1) v += __shfl_xor(v, o);
    __shared__ int ws[4];
    if ((t & 63) == 0) ws[t >> 6] = v;
    __syncthreads();
    if (t == 0) bsum[blockIdx.x] = ws[0] + ws[1] + ws[2] + ws[3];
}

// ---------------------------------------------------------------------------
// 3b. Scan 196 bin counts -> coarse_start[197] (+ cursor copy); row_start[N]=E.
// ---------------------------------------------------------------------------
__global__ __launch_bounds__(256) void k_scan196(const int* __restrict__ bsum,
                                                 int* __restrict__ coarse_start,
                                                 int* __restrict__ coarse_cursor,
                                                 int* __restrict__ row_start) {
    __shared__ int s[256];
    int t = threadIdx.x;
    int v = (t < NBIN_) ? bsum[t] : 0;
    s[t] = v;
    __syncthreads();
    for (int o = 1; o < 256; o <<= 1) {
        int u = (t >= o) ? s[t - o] : 0;
        __syncthreads();
        s[t] += u;
        __syncthreads();
    }
    int excl = s[t] - v;
    if (t <= NBIN_) { coarse_start[t] = excl; coarse_cursor[t] = excl; }
    if (t == 0) row_start[N_] = E_;
}

// ---------------------------------------------------------------------------
// 3c. row_start: block-local exclusive scan of cnt + coarse_start offset.
// ---------------------------------------------------------------------------
__global__ __launch_bounds__(256) void k_rowstart(const int* __restrict__ cnt,
                                                  const int* __restrict__ coarse_start,
                                                  int* __restrict__ row_start) {
    __shared__ int s[256];
    int t = threadIdx.x, n = (blockIdx.x << 8) + t;
    int v = (n < N_) ? cnt[n] : 0;
    s[t] = v;
    __syncthreads();
    for (int o = 1; o < 256; o <<= 1) {
        int u = (t >= o) ? s[t - o] : 0;
        __syncthreads();
        s[t] += u;
        __syncthreads();
    }
    if (n < N_) row_start[n] = coarse_start[blockIdx.x] + (s[t] - v);
}

// ---------------------------------------------------------------------------
// 4a. Coarse binning: per-block LDS histogram over dst>>8; one global atomic
//     per (block,bin) reserves space; (src,dst) written grouped by bin.
// ---------------------------------------------------------------------------
constexpr int EPB_ = 4096;   // edges per block
__global__ __launch_bounds__(256) void k_bin(const int* __restrict__ src,
                                             const int* __restrict__ dst,
                                             int* __restrict__ coarse_cursor,
                                             uint2* __restrict__ binned) {
    __shared__ int hist[256], base[256];
    int t = threadIdx.x;
    int e0 = blockIdx.x * EPB_;
    hist[t] = 0;
    __syncthreads();
#pragma unroll
    for (int i = 0; i < EPB_ / 256; ++i) {
        int e = e0 + i * 256 + t;
        if (e < E_) atomicAdd(&hist[dst[e] >> 8], 1);
    }
    __syncthreads();
    if (t < NBIN_ && hist[t]) base[t] = atomicAdd(&coarse_cursor[t], hist[t]);
    __syncthreads();
#pragma unroll
    for (int i = 0; i < EPB_ / 256; ++i) {
        int e = e0 + i * 256 + t;
        if (e < E_) {
            int d = dst[e];
            int pos = atomicAdd(&base[d >> 8], 1);
            binned[pos] = make_uint2((unsigned int)src[e], (unsigned int)d);
        }
    }
}

// ---------------------------------------------------------------------------
// 4b. Final fill: one block per coarse bin; cursors in LDS; scatter lands in
//     a ~32KB window (L2-resident, lines fill completely).
// ---------------------------------------------------------------------------
__global__ __launch_bounds__(256) void k_fill2(const uint2* __restrict__ binned,
                                               const int* __restrict__ coarse_start,
                                               const int* __restrict__ row_start,
                                               int* __restrict__ sorted_src) {
    __shared__ int cur[256];
    int t = threadIdx.x;
    int n0 = blockIdx.x << 8;
    if (n0 + t < N_) cur[t] = row_start[n0 + t];
    __syncthreads();
    int beg = coarse_start[blockIdx.x], end = coarse_start[blockIdx.x + 1];
    for (int j = beg + t; j < end; j += 256) {
        uint2 e = binned[j];
        int pos = atomicAdd(&cur[e.y - (unsigned int)n0], 1);
        sorted_src[pos] = (int)e.x;
    }
}

// ---------------------------------------------------------------------------
// 5. Quarter-dim gather pass: agg[n][Q-slice] from 3.2MB XCD-L2-resident slice.
//    Wave per node; lanes: jj=lane>>4 handles edges j%4==jj, c=lane&15 is the
//    u32 column within the quarter. One load instruction = 4 rows x 64B.
// ---------------------------------------------------------------------------
template<int Q>
__global__ __launch_bounds__(256) void k_gather_q(const int* __restrict__ row_start,
                                                  const int* __restrict__ sorted_src,
                                                  const float* __restrict__ disq,
                                                  const float* __restrict__ dinv,
                                                  const unsigned int* __restrict__ v,
                                                  float2* __restrict__ agg) {
    int n = blockIdx.x * 4 + (threadIdx.x >> 6);
    if (n >= N_) return;
    int lane = threadIdx.x & 63;
    int jj = lane >> 4, c = lane & 15;
    int col = Q * 16 + c;
    int beg = row_start[n], end = row_start[n + 1];
    float ax = 0.f, ay = 0.f;
    int j = beg + jj;
    // 4-step unroll: 16 rows in flight per wave
    for (; j + 12 < end; j += 16) {
        int s0 = sorted_src[j],      s1 = sorted_src[j + 4];
        int s2 = sorted_src[j + 8],  s3 = sorted_src[j + 12];
        float w0 = disq[s0], w1 = disq[s1], w2 = disq[s2], w3 = disq[s3];
        unsigned int b0 = v[(size_t)s0 * 64 + col];
        unsigned int b1 = v[(size_t)s1 * 64 + col];
        unsigned int b2 = v[(size_t)s2 * 64 + col];
        unsigned int b3 = v[(size_t)s3 * 64 + col];
        ax = fmaf(w0, blo(b0), ax); ay = fmaf(w0, bhi(b0), ay);
        ax = fmaf(w1, blo(b1), ax); ay = fmaf(w1, bhi(b1), ay);
        ax = fmaf(w2, blo(b2), ax); ay = fmaf(w2, bhi(b2), ay);
        ax = fmaf(w3, blo(b3), ax); ay = fmaf(w3, bhi(b3), ay);
    }
    for (; j < end; j += 4) {
        int s = sorted_src[j];
        float w = disq[s];
        unsigned int b = v[(size_t)s * 64 + col];
        ax = fmaf(w, blo(b), ax); ay = fmaf(w, bhi(b), ay);
    }
    ax += __shfl_xor(ax, 16); ax += __shfl_xor(ax, 32);
    ay += __shfl_xor(ay, 16); ay += __shfl_xor(ay, 32);
    if (jj == 0) {
        float dq = disq[n], di = dinv[n];
        unsigned int bs = v[(size_t)n * 64 + col];
        float rx = fmaf(di, blo(bs), ax * dq);
        float ry = fmaf(di, bhi(bs), ay * dq);
        agg[(size_t)n * 64 + col] = make_float2(rx, ry);
    }
}

// ---------------------------------------------------------------------------
// 6. Register-blocked GEMM: h = relu(agg @ W1 + b1), bf16 output.
// ---------------------------------------------------------------------------
__global__ __launch_bounds__(256, 2) void k_gemm_relu(const float* __restrict__ u,
                                                      const float* __restrict__ W,
                                                      const float* __restrict__ b,
                                                      unsigned short* __restrict__ hout) {
    __shared__ float lw[D_ * D_];     // 64 KiB
    __shared__ float lu[32 * D_];     // 16 KiB
    int tid = threadIdx.x;
    for (int t = tid; t < D_ * D_ / 4; t += 256)
        ((float4*)lw)[t] = ((const float4*)W)[t];

    int l  = tid & 31;
    int rl = ((tid >> 6) << 3) + (((tid >> 5) & 1) << 2);
    float4 bb = ((const float4*)b)[l];

    for (int tile = blockIdx.x; tile * 32 < N_; tile += gridDim.x) {
        int row0 = tile * 32;
        __syncthreads();
#pragma unroll
        for (int i = 0; i < 4; ++i) {
            int flat = i * 256 + tid;
            int r = flat >> 5, c4 = flat & 31;
            int gr = row0 + r;
            ((float4*)lu)[flat] = (gr < N_) ? ((const float4*)u)[(size_t)gr * 32 + c4]
                                            : make_float4(0.f, 0.f, 0.f, 0.f);
        }
        __syncthreads();
        float4 a0 = {0,0,0,0}, a1 = {0,0,0,0}, a2 = {0,0,0,0}, a3 = {0,0,0,0};
#pragma unroll 4
        for (int k4 = 0; k4 < 32; ++k4) {
            int k = k4 * 4;
            float4 w0 = ((const float4*)(lw + (k + 0) * D_))[l];
            float4 w1 = ((const float4*)(lw + (k + 1) * D_))[l];
            float4 w2 = ((const float4*)(lw + (k + 2) * D_))[l];
            float4 w3 = ((const float4*)(lw + (k + 3) * D_))[l];
            float4 u0 = ((const float4*)(lu + (rl + 0) * D_))[k4];
            float4 u1 = ((const float4*)(lu + (rl + 1) * D_))[k4];
            float4 u2 = ((const float4*)(lu + (rl + 2) * D_))[k4];
            float4 u3 = ((const float4*)(lu + (rl + 3) * D_))[k4];
            a0 = fma4(u0.x, w0, fma4(u0.y, w1, fma4(u0.z, w2, fma4(u0.w, w3, a0))));
            a1 = fma4(u1.x, w0, fma4(u1.y, w1, fma4(u1.z, w2, fma4(u1.w, w3, a1))));
            a2 = fma4(u2.x, w0, fma4(u2.y, w1, fma4(u2.z, w2, fma4(u2.w, w3, a2))));
            a3 = fma4(u3.x, w0, fma4(u3.y, w1, fma4(u3.z, w2, fma4(u3.w, w3, a3))));
        }
        float4 accs[4] = {a0, a1, a2, a3};
#pragma unroll
        for (int r = 0; r < 4; ++r) {
            int row = row0 + rl + r;
            if (row < N_) {
                float4 a = accs[r];
                ushort4 o;
                o.x = f2bf(fmaxf(a.x + bb.x, 0.f));
                o.y = f2bf(fmaxf(a.y + bb.y, 0.f));
                o.z = f2bf(fmaxf(a.z + bb.z, 0.f));
                o.w = f2bf(fmaxf(a.w + bb.w, 0.f));
                ((ushort4*)hout)[(size_t)row * 32 + l] = o;
            }
        }
    }
}

// ---------------------------------------------------------------------------
// 7. Fused mu/logstd GEMM (columns interleaved); z = mu + noise*exp(ls), bf16.
// ---------------------------------------------------------------------------
__global__ __launch_bounds__(256, 2) void k_gemm_z(const float* __restrict__ g,
                                                   const float* __restrict__ Wmu,
                                                   const float* __restrict__ bmu,
                                                   const float* __restrict__ Wls,
                                                   const float* __restrict__ bls,
                                                   const float* __restrict__ noise,
                                                   unsigned int* __restrict__ z) {
    __shared__ float lw[D_ * D_];     // 64 KiB (interleaved Wmu|Wls)
    __shared__ float lu[32 * D_];     // 16 KiB
    int tid = threadIdx.x;
    for (int t = tid; t < D_ * 32; t += 256) {
        int k = t >> 5, j2 = t & 31;
        float2 m2 = ((const float2*)Wmu)[k * 32 + j2];
        float2 l2 = ((const float2*)Wls)[k * 32 + j2];
        ((float4*)lw)[t] = make_float4(m2.x, l2.x, m2.y, l2.y);
    }

    int l  = tid & 31;
    int rl = ((tid >> 6) << 3) + (((tid >> 5) & 1) << 2);
    float2 bm = ((const float2*)bmu)[l];
    float2 bl = ((const float2*)bls)[l];
    float4 bb = make_float4(bm.x, bl.x, bm.y, bl.y);

    for (int tile = blockIdx.x; tile * 32 < N_; tile += gridDim.x) {
        int row0 = tile * 32;
        __syncthreads();
#pragma unroll
        for (int i = 0; i < 4; ++i) {
            int flat = i * 256 + tid;
            int r = flat >> 5, c4 = flat & 31;
            int gr = row0 + r;
            ((float4*)lu)[flat] = (gr < N_) ? ((const float4*)g)[(size_t)gr * 32 + c4]
                                            : make_float4(0.f, 0.f, 0.f, 0.f);
        }
        __syncthreads();
        float4 a0 = {0,0,0,0}, a1 = {0,0,0,0}, a2 = {0,0,0,0}, a3 = {0,0,0,0};
#pragma unroll 4
        for (int k4 = 0; k4 < 32; ++k4) {
            int k = k4 * 4;
            float4 w0 = ((const float4*)(lw + (k + 0) * D_))[l];
            float4 w1 = ((const float4*)(lw + (k + 1) * D_))[l];
            float4 w2 = ((const float4*)(lw + (k + 2) * D_))[l];
            float4 w3 = ((const float4*)(lw + (k + 3) * D_))[l];
            float4 u0 = ((const float4*)(lu + (rl + 0) * D_))[k4];
            float4 u1 = ((const float4*)(lu + (rl + 1) * D_))[k4];
            float4 u2 = ((const float4*)(lu + (rl + 2) * D_))[k4];
            float4 u3 = ((const float4*)(lu + (rl + 3) * D_))[k4];
            a0 = fma4(u0.x, w0, fma4(u0.y, w1, fma4(u0.z, w2, fma4(u0.w, w3, a0))));
            a1 = fma4(u1.x, w0, fma4(u1.y, w1, fma4(u1.z, w2, fma4(u1.w, w3, a1))));
            a2 = fma4(u2.x, w0, fma4(u2.y, w1, fma4(u2.z, w2, fma4(u2.w, w3, a2))));
            a3 = fma4(u3.x, w0, fma4(u3.y, w1, fma4(u3.z, w2, fma4(u3.w, w3, a3))));
        }
        float4 accs[4] = {a0, a1, a2, a3};
#pragma unroll
        for (int r = 0; r < 4; ++r) {
            int row = row0 + rl + r;
            if (row < N_) {
                float4 a = accs[r];
                float2 n2 = ((const float2*)noise)[(size_t)row * 32 + l];
                float z0 = (a.x + bb.x) + n2.x * expf(a.y + bb.y);
                float z1 = (a.z + bb.z) + n2.y * expf(a.w + bb.w);
                z[(size_t)row * 32 + l] =
                    (unsigned int)f2bf(z0) | ((unsigned int)f2bf(z1) << 16);
            }
        }
    }
}

// ---------------------------------------------------------------------------
// 8. Decoder, half-dim pass: partial dot over 32 dims (64B-aligned slice of z;
//    3.2MB working set = XCD-L2 resident). 8 lanes per edge. Pass 1 adds.
// ---------------------------------------------------------------------------
template<int HALF>
__global__ __launch_bounds__(256) void k_decode_h(const int* __restrict__ src,
                                                  const int* __restrict__ dst,
                                                  const unsigned int* __restrict__ z,
                                                  float* __restrict__ out) {
    int e = blockIdx.x * 32 + (threadIdx.x >> 3);
    if (e >= E_) return;
    int l = threadIdx.x & 7;
    int s = src[e], d = dst[e];
    uint2 za = ((const uint2*)z)[(size_t)s * 16 + HALF * 8 + l];
    uint2 zb = ((const uint2*)z)[(size_t)d * 16 + HALF * 8 + l];
    float p = blo(za.x) * blo(zb.x) + bhi(za.x) * bhi(zb.x)
            + blo(za.y) * blo(zb.y) + bhi(za.y) * bhi(zb.y);
#pragma unroll
    for (int o = 4; o; o >>= 1) p += __shfl_xor(p, o);
    if (l == 0) out[e] = HALF ? out[e] + p : p;
}

// ---------------------------------------------------------------------------
extern "C" void kernel_launch(void* const* d_in, const int* in_sizes, int n_in,
                              void* d_out, int out_size, void* d_ws, size_t ws_size,
                              hipStream_t stream) {
    const int*   fi    = (const int*)d_in[0];
    const float* fw    = (const float*)d_in[2];
    const int*   ei    = (const int*)d_in[3];
    const float* noise = (const float*)d_in[4];
    const float* emb   = (const float*)d_in[5];
    const float* W1    = (const float*)d_in[6];
    const float* b1    = (const float*)d_in[7];
    const float* Wmu   = (const float*)d_in[8];
    const float* bmu   = (const float*)d_in[9];
    const float* Wls   = (const float*)d_in[10];
    const float* bls   = (const float*)d_in[11];
    float* out = (float*)d_out;

    const int* src = ei;
    const int* dst = ei + E_;

    // Workspace layout (4-byte units). The 25.6MB "alias" region serves, in
    // non-overlapping lifetime order: emb_bf (cvt->embed), binned (bin->fill2),
    // agg (gather->gemm).
    float*        ws        = (float*)d_ws;
    float*        agg       = ws;                                    // N*128 f32 = 25.6MB
    unsigned int* emb_bf    = (unsigned int*)agg;                    // V*64 u32 = 25.6MB
    uint2*        binned    = (uint2*)agg;                           // E uint2 = 12.8MB
    unsigned int* x         = (unsigned int*)(agg + (size_t)N_ * D_);// N*64 u32
    unsigned int* h         = x + (size_t)N_ * 64;                   // N*64 u32
    unsigned int* z         = h + (size_t)N_ * 64;                   // N*32 u32
    float*        disq      = (float*)(z + (size_t)N_ * 32);         // N
    float*        dinv      = disq + N_;                             // N
    int*          cnt       = (int*)(dinv + N_);                     // N
    int*          row_start = cnt + N_;                              // N+1
    int*          sorted_src= row_start + (N_ + 1);                  // E
    int*          bsum      = sorted_src + E_;                       // NBIN
    int*          coarse_start  = bsum + 256;                        // NBIN+1
    int*          coarse_cursor = coarse_start + 256;                // NBIN+1

    hipMemsetAsync(cnt, 0, N_ * sizeof(int), stream);

    k_cvt    <<<(V_ * D_ / 8 + 255) / 256, 256, 0, stream>>>(emb, emb_bf);
    k_embed  <<<N_ / 4,            256, 0, stream>>>(fi, fw, emb_bf, x);
    k_degcnt <<<(E_ + 255) / 256,  256, 0, stream>>>(dst, cnt);
    k_degnorm<<<(N_ + 255) / 256,  256, 0, stream>>>(cnt, disq, dinv);
    k_bsum   <<<NBIN_,             256, 0, stream>>>(cnt, bsum);
    k_scan196<<<1,                 256, 0, stream>>>(bsum, coarse_start, coarse_cursor,
                                                     row_start);
    k_rowstart<<<NBIN_,            256, 0, stream>>>(cnt, coarse_start, row_start);
    k_bin    <<<(E_ + EPB_ - 1) / EPB_, 256, 0, stream>>>(src, dst, coarse_cursor, binned);
    k_fill2  <<<NBIN_,             256, 0, stream>>>(binned, coarse_start, row_start,
                                                     sorted_src);

    // GCN layer 1: 4 quarter-dim gather passes (3.2MB slice each), then GEMM
    k_gather_q<0><<<N_ / 4, 256, 0, stream>>>(row_start, sorted_src, disq, dinv, x, (float2*)agg);
    k_gather_q<1><<<N_ / 4, 256, 0, stream>>>(row_start, sorted_src, disq, dinv, x, (float2*)agg);
    k_gather_q<2><<<N_ / 4, 256, 0, stream>>>(row_start, sorted_src, disq, dinv, x, (float2*)agg);
    k_gather_q<3><<<N_ / 4, 256, 0, stream>>>(row_start, sorted_src, disq, dinv, x, (float2*)agg);
    k_gemm_relu<<<512,      256, 0, stream>>>(agg, W1, b1, (unsigned short*)h);

    // GCN layers 2+3
    k_gather_q<0><<<N_ / 4, 256, 0, stream>>>(row_start, sorted_src, disq, dinv, h, (float2*)agg);
    k_gather_q<1><<<N_ / 4, 256, 0, stream>>>(row_start, sorted_src, disq, dinv, h, (float2*)agg);
    k_gather_q<2><<<N_ / 4, 256, 0, stream>>>(row_start, sorted_src, disq, dinv, h, (float2*)agg);
    k_gather_q<3><<<N_ / 4, 256, 0, stream>>>(row_start, sorted_src, disq, dinv, h, (float2*)agg);
    k_gemm_z <<<512,        256, 0, stream>>>(agg, Wmu, bmu, Wls, bls, noise, z);

    // Decoder: 2 half-dim passes (3.2MB slice each)
    k_decode_h<0><<<E_ / 32, 256, 0, stream>>>(src, dst, z, out);
    k_decode_h<1><<<E_ / 32, 256, 0, stream>>>(src, dst, z, out);
}

// Round 7
// 489.831 us; speedup vs baseline: 1.3860x; 1.3860x over previous
//
#include <hip/hip_runtime.h>
#include <hip/hip_bf16.h>

// VGAE forward, MI355X. Gather-based GCN; bf16 storage for all gathered operands.
// CSR build via two-level binned counting sort; all per-node counts are derived
// inside the binned domain (LDS atomics only, no random global atomics).
constexpr int N_ = 50000;
constexpr int E_ = 1600000;
constexpr int D_ = 128;   // embedding_dim == hidden_dim
constexpr int O_ = 64;    // out_embedding_dim
constexpr int NNZ_ = 16;
constexpr int V_ = 100000;
constexpr int NBIN_ = (N_ + 255) / 256;   // 196 coarse bins (dst>>8)

static __device__ __forceinline__ unsigned short f2bf(float f) {
    __hip_bfloat16 h = __float2bfloat16(f);
    return __builtin_bit_cast(unsigned short, h);
}
static __device__ __forceinline__ float blo(unsigned int u) { return __uint_as_float(u << 16); }
static __device__ __forceinline__ float bhi(unsigned int u) { return __uint_as_float(u & 0xffff0000u); }
static __device__ __forceinline__ float4 fma4(float s, float4 a, float4 b) {
    return make_float4(fmaf(s, a.x, b.x), fmaf(s, a.y, b.y),
                       fmaf(s, a.z, b.z), fmaf(s, a.w, b.w));
}

// ---------------------------------------------------------------------------
// 0. Convert fp32 emb table [V][128] -> bf16 (packed u32 pairs).
// ---------------------------------------------------------------------------
__global__ __launch_bounds__(256) void k_cvt(const float* __restrict__ emb,
                                             unsigned int* __restrict__ emb_bf) {
    int t = blockIdx.x * blockDim.x + threadIdx.x;
    if (t >= V_ * D_ / 8) return;
    float4 a = ((const float4*)emb)[t * 2];
    float4 b = ((const float4*)emb)[t * 2 + 1];
    uint4 o;
    o.x = (unsigned int)f2bf(a.x) | ((unsigned int)f2bf(a.y) << 16);
    o.y = (unsigned int)f2bf(a.z) | ((unsigned int)f2bf(a.w) << 16);
    o.z = (unsigned int)f2bf(b.x) | ((unsigned int)f2bf(b.y) << 16);
    o.w = (unsigned int)f2bf(b.z) | ((unsigned int)f2bf(b.w) << 16);
    ((uint4*)emb_bf)[t] = o;
}

// ---------------------------------------------------------------------------
// 1. EmbeddingBag(sum) + L2 normalize from bf16 table. One wave per node.
// ---------------------------------------------------------------------------
__global__ __launch_bounds__(256) void k_embed(const int* __restrict__ fi,
                                               const float* __restrict__ fw,
                                               const unsigned int* __restrict__ emb_bf,
                                               unsigned int* __restrict__ x) {
    int n = blockIdx.x * 4 + (threadIdx.x >> 6);
    if (n >= N_) return;
    int lane = threadIdx.x & 63;
    float a0 = 0.f, a1 = 0.f;
    int base = n * NNZ_;
#pragma unroll
    for (int j = 0; j < NNZ_; ++j) {
        int idx  = fi[base + j];
        float w  = fw[base + j];
        unsigned int r = emb_bf[(size_t)idx * 64 + lane];
        a0 = fmaf(w, blo(r), a0);
        a1 = fmaf(w, bhi(r), a1);
    }
    float ss = a0 * a0 + a1 * a1;
#pragma unroll
    for (int o = 32; o; o >>= 1) ss += __shfl_xor(ss, o);
    float sc = 1.0f / fmaxf(sqrtf(ss), 1e-12f);
    x[(size_t)n * 64 + lane] =
        (unsigned int)f2bf(a0 * sc) | ((unsigned int)f2bf(a1 * sc) << 16);
}

// ---------------------------------------------------------------------------
// 2a. Coarse-bin histogram of dst>>8: LDS hist per block, 196 global atomics.
// ---------------------------------------------------------------------------
constexpr int EPB_ = 4096;   // edges per block
__global__ __launch_bounds__(256) void k_bhist(const int* __restrict__ dst,
                                               int* __restrict__ bin_total) {
    __shared__ int hist[256];
    int t = threadIdx.x;
    hist[t] = 0;
    __syncthreads();
    int e0 = blockIdx.x * EPB_;
#pragma unroll
    for (int i = 0; i < EPB_ / 256; ++i) {
        int e = e0 + i * 256 + t;
        if (e < E_) atomicAdd(&hist[dst[e] >> 8], 1);
    }
    __syncthreads();
    if (t < NBIN_ && hist[t]) atomicAdd(&bin_total[t], hist[t]);
}

// ---------------------------------------------------------------------------
// 2b. Scan 196 bin counts -> coarse_start[197] (+ cursor copy); row_start[N]=E.
// ---------------------------------------------------------------------------
__global__ __launch_bounds__(256) void k_scan196(const int* __restrict__ bin_total,
                                                 int* __restrict__ coarse_start,
                                                 int* __restrict__ coarse_cursor,
                                                 int* __restrict__ row_start) {
    __shared__ int s[256];
    int t = threadIdx.x;
    int v = (t < NBIN_) ? bin_total[t] : 0;
    s[t] = v;
    __syncthreads();
    for (int o = 1; o < 256; o <<= 1) {
        int u = (t >= o) ? s[t - o] : 0;
        __syncthreads();
        s[t] += u;
        __syncthreads();
    }
    int excl = s[t] - v;
    if (t <= NBIN_) { coarse_start[t] = excl; coarse_cursor[t] = excl; }
    if (t == 0) row_start[N_] = E_;
}

// ---------------------------------------------------------------------------
// 2c. Coarse binning: LDS histogram + one global atomic per (block,bin) to
//     reserve space; edges written grouped by bin, packed src|dlow<<16 (u32).
// ---------------------------------------------------------------------------
__global__ __launch_bounds__(256) void k_bin(const int* __restrict__ src,
                                             const int* __restrict__ dst,
                                             int* __restrict__ coarse_cursor,
                                             unsigned int* __restrict__ binned) {
    __shared__ int hist[256], base[256];
    int t = threadIdx.x;
    int e0 = blockIdx.x * EPB_;
    hist[t] = 0;
    __syncthreads();
#pragma unroll
    for (int i = 0; i < EPB_ / 256; ++i) {
        int e = e0 + i * 256 + t;
        if (e < E_) atomicAdd(&hist[dst[e] >> 8], 1);
    }
    __syncthreads();
    if (t < NBIN_ && hist[t]) base[t] = atomicAdd(&coarse_cursor[t], hist[t]);
    __syncthreads();
#pragma unroll
    for (int i = 0; i < EPB_ / 256; ++i) {
        int e = e0 + i * 256 + t;
        if (e < E_) {
            int d = dst[e];
            int pos = atomicAdd(&base[d >> 8], 1);
            binned[pos] = (unsigned int)src[e] | ((unsigned int)(d & 255) << 16);
        }
    }
}

// ---------------------------------------------------------------------------
// 2d. Per-node degree (LDS hist of binned slice) -> disq, dinv, row_start.
//     One block per coarse bin; no global atomics.
// ---------------------------------------------------------------------------
__global__ __launch_bounds__(256) void k_node(const unsigned int* __restrict__ binned,
                                              const int* __restrict__ coarse_start,
                                              float* __restrict__ disq,
                                              float* __restrict__ dinv,
                                              int* __restrict__ row_start) {
    __shared__ int hist[256], s[256];
    int t = threadIdx.x;
    hist[t] = 0;
    __syncthreads();
    int beg = coarse_start[blockIdx.x], end = coarse_start[blockIdx.x + 1];
    for (int j = beg + t; j < end; j += 256)
        atomicAdd(&hist[(binned[j] >> 16) & 255], 1);
    __syncthreads();
    int v = hist[t];
    int n = (blockIdx.x << 8) + t;
    if (n < N_) {
        float deg = 1.0f + (float)v;
        disq[n] = rsqrtf(deg);
        dinv[n] = 1.0f / deg;
    }
    s[t] = v;
    __syncthreads();
    for (int o = 1; o < 256; o <<= 1) {
        int u = (t >= o) ? s[t - o] : 0;
        __syncthreads();
        s[t] += u;
        __syncthreads();
    }
    if (n < N_) row_start[n] = beg + (s[t] - v);
}

// ---------------------------------------------------------------------------
// 2e. Final fill: one block per coarse bin; cursors in LDS; writes land in a
//     ~32KB window (L2-resident, lines fill completely).
// ---------------------------------------------------------------------------
__global__ __launch_bounds__(256) void k_fill2(const unsigned int* __restrict__ binned,
                                               const int* __restrict__ coarse_start,
                                               const int* __restrict__ row_start,
                                               int* __restrict__ sorted_src) {
    __shared__ int cur[256];
    int t = threadIdx.x;
    int n0 = blockIdx.x << 8;
    if (n0 + t < N_) cur[t] = row_start[n0 + t];
    __syncthreads();
    int beg = coarse_start[blockIdx.x], end = coarse_start[blockIdx.x + 1];
    for (int j = beg + t; j < end; j += 256) {
        unsigned int b = binned[j];
        int pos = atomicAdd(&cur[(b >> 16) & 255], 1);
        sorted_src[pos] = (int)(b & 0xFFFFu);
    }
}

// ---------------------------------------------------------------------------
// 3. Gather aggregation from bf16 rows:
//    agg[n] = disq[n] * sum_j disq[s_j]*v[s_j]  +  dinv[n]*v[n]
// ---------------------------------------------------------------------------
__global__ __launch_bounds__(256) void k_gather(const int* __restrict__ row_start,
                                                const int* __restrict__ sorted_src,
                                                const float* __restrict__ disq,
                                                const float* __restrict__ dinv,
                                                const unsigned int* __restrict__ v,
                                                float* __restrict__ agg) {
    int n = blockIdx.x * 4 + (threadIdx.x >> 6);
    if (n >= N_) return;
    int lane = threadIdx.x & 63;
    int beg = row_start[n], end = row_start[n + 1];
    float ax = 0.f, ay = 0.f;
    int j = beg;
    for (; j + 7 < end; j += 8) {
        int s0 = sorted_src[j],     s1 = sorted_src[j + 1];
        int s2 = sorted_src[j + 2], s3 = sorted_src[j + 3];
        int s4 = sorted_src[j + 4], s5 = sorted_src[j + 5];
        int s6 = sorted_src[j + 6], s7 = sorted_src[j + 7];
        float w0 = disq[s0], w1 = disq[s1], w2 = disq[s2], w3 = disq[s3];
        float w4 = disq[s4], w5 = disq[s5], w6 = disq[s6], w7 = disq[s7];
        unsigned int b0 = v[(size_t)s0 * 64 + lane];
        unsigned int b1 = v[(size_t)s1 * 64 + lane];
        unsigned int b2 = v[(size_t)s2 * 64 + lane];
        unsigned int b3 = v[(size_t)s3 * 64 + lane];
        unsigned int b4 = v[(size_t)s4 * 64 + lane];
        unsigned int b5 = v[(size_t)s5 * 64 + lane];
        unsigned int b6 = v[(size_t)s6 * 64 + lane];
        unsigned int b7 = v[(size_t)s7 * 64 + lane];
        ax = fmaf(w0, blo(b0), ax); ay = fmaf(w0, bhi(b0), ay);
        ax = fmaf(w1, blo(b1), ax); ay = fmaf(w1, bhi(b1), ay);
        ax = fmaf(w2, blo(b2), ax); ay = fmaf(w2, bhi(b2), ay);
        ax = fmaf(w3, blo(b3), ax); ay = fmaf(w3, bhi(b3), ay);
        ax = fmaf(w4, blo(b4), ax); ay = fmaf(w4, bhi(b4), ay);
        ax = fmaf(w5, blo(b5), ax); ay = fmaf(w5, bhi(b5), ay);
        ax = fmaf(w6, blo(b6), ax); ay = fmaf(w6, bhi(b6), ay);
        ax = fmaf(w7, blo(b7), ax); ay = fmaf(w7, bhi(b7), ay);
    }
    for (; j < end; ++j) {
        int s = sorted_src[j];
        float w = disq[s];
        unsigned int b = v[(size_t)s * 64 + lane];
        ax = fmaf(w, blo(b), ax); ay = fmaf(w, bhi(b), ay);
    }
    float dq = disq[n], di = dinv[n];
    unsigned int bs = v[(size_t)n * 64 + lane];
    ax = fmaf(di, blo(bs), ax * dq);
    ay = fmaf(di, bhi(bs), ay * dq);
    ((float2*)agg)[(size_t)n * 64 + lane] = make_float2(ax, ay);
}

// ---------------------------------------------------------------------------
// 4. Register-blocked GEMM: h = relu(agg @ W1 + b1), bf16 output.
// ---------------------------------------------------------------------------
__global__ __launch_bounds__(256, 2) void k_gemm_relu(const float* __restrict__ u,
                                                      const float* __restrict__ W,
                                                      const float* __restrict__ b,
                                                      unsigned short* __restrict__ hout) {
    __shared__ float lw[D_ * D_];     // 64 KiB
    __shared__ float lu[32 * D_];     // 16 KiB
    int tid = threadIdx.x;
    for (int t = tid; t < D_ * D_ / 4; t += 256)
        ((float4*)lw)[t] = ((const float4*)W)[t];

    int l  = tid & 31;
    int rl = ((tid >> 6) << 3) + (((tid >> 5) & 1) << 2);
    float4 bb = ((const float4*)b)[l];

    for (int tile = blockIdx.x; tile * 32 < N_; tile += gridDim.x) {
        int row0 = tile * 32;
        __syncthreads();
#pragma unroll
        for (int i = 0; i < 4; ++i) {
            int flat = i * 256 + tid;
            int r = flat >> 5, c4 = flat & 31;
            int gr = row0 + r;
            ((float4*)lu)[flat] = (gr < N_) ? ((const float4*)u)[(size_t)gr * 32 + c4]
                                            : make_float4(0.f, 0.f, 0.f, 0.f);
        }
        __syncthreads();
        float4 a0 = {0,0,0,0}, a1 = {0,0,0,0}, a2 = {0,0,0,0}, a3 = {0,0,0,0};
#pragma unroll 4
        for (int k4 = 0; k4 < 32; ++k4) {
            int k = k4 * 4;
            float4 w0 = ((const float4*)(lw + (k + 0) * D_))[l];
            float4 w1 = ((const float4*)(lw + (k + 1) * D_))[l];
            float4 w2 = ((const float4*)(lw + (k + 2) * D_))[l];
            float4 w3 = ((const float4*)(lw + (k + 3) * D_))[l];
            float4 u0 = ((const float4*)(lu + (rl + 0) * D_))[k4];
            float4 u1 = ((const float4*)(lu + (rl + 1) * D_))[k4];
            float4 u2 = ((const float4*)(lu + (rl + 2) * D_))[k4];
            float4 u3 = ((const float4*)(lu + (rl + 3) * D_))[k4];
            a0 = fma4(u0.x, w0, fma4(u0.y, w1, fma4(u0.z, w2, fma4(u0.w, w3, a0))));
            a1 = fma4(u1.x, w0, fma4(u1.y, w1, fma4(u1.z, w2, fma4(u1.w, w3, a1))));
            a2 = fma4(u2.x, w0, fma4(u2.y, w1, fma4(u2.z, w2, fma4(u2.w, w3, a2))));
            a3 = fma4(u3.x, w0, fma4(u3.y, w1, fma4(u3.z, w2, fma4(u3.w, w3, a3))));
        }
        float4 accs[4] = {a0, a1, a2, a3};
#pragma unroll
        for (int r = 0; r < 4; ++r) {
            int row = row0 + rl + r;
            if (row < N_) {
                float4 a = accs[r];
                ushort4 o;
                o.x = f2bf(fmaxf(a.x + bb.x, 0.f));
                o.y = f2bf(fmaxf(a.y + bb.y, 0.f));
                o.z = f2bf(fmaxf(a.z + bb.z, 0.f));
                o.w = f2bf(fmaxf(a.w + bb.w, 0.f));
                ((ushort4*)hout)[(size_t)row * 32 + l] = o;
            }
        }
    }
}

// ---------------------------------------------------------------------------
// 5. Fused mu/logstd GEMM (columns interleaved); z = mu + noise*exp(ls), bf16.
// ---------------------------------------------------------------------------
__global__ __launch_bounds__(256, 2) void k_gemm_z(const float* __restrict__ g,
                                                   const float* __restrict__ Wmu,
                                                   const float* __restrict__ bmu,
                                                   const float* __restrict__ Wls,
                                                   const float* __restrict__ bls,
                                                   const float* __restrict__ noise,
                                                   unsigned int* __restrict__ z) {
    __shared__ float lw[D_ * D_];     // 64 KiB (interleaved Wmu|Wls)
    __shared__ float lu[32 * D_];     // 16 KiB
    int tid = threadIdx.x;
    for (int t = tid; t < D_ * 32; t += 256) {
        int k = t >> 5, j2 = t & 31;
        float2 m2 = ((const float2*)Wmu)[k * 32 + j2];
        float2 l2 = ((const float2*)Wls)[k * 32 + j2];
        ((float4*)lw)[t] = make_float4(m2.x, l2.x, m2.y, l2.y);
    }

    int l  = tid & 31;
    int rl = ((tid >> 6) << 3) + (((tid >> 5) & 1) << 2);
    float2 bm = ((const float2*)bmu)[l];
    float2 bl = ((const float2*)bls)[l];
    float4 bb = make_float4(bm.x, bl.x, bm.y, bl.y);

    for (int tile = blockIdx.x; tile * 32 < N_; tile += gridDim.x) {
        int row0 = tile * 32;
        __syncthreads();
#pragma unroll
        for (int i = 0; i < 4; ++i) {
            int flat = i * 256 + tid;
            int r = flat >> 5, c4 = flat & 31;
            int gr = row0 + r;
            ((float4*)lu)[flat] = (gr < N_) ? ((const float4*)g)[(size_t)gr * 32 + c4]
                                            : make_float4(0.f, 0.f, 0.f, 0.f);
        }
        __syncthreads();
        float4 a0 = {0,0,0,0}, a1 = {0,0,0,0}, a2 = {0,0,0,0}, a3 = {0,0,0,0};
#pragma unroll 4
        for (int k4 = 0; k4 < 32; ++k4) {
            int k = k4 * 4;
            float4 w0 = ((const float4*)(lw + (k + 0) * D_))[l];
            float4 w1 = ((const float4*)(lw + (k + 1) * D_))[l];
            float4 w2 = ((const float4*)(lw + (k + 2) * D_))[l];
            float4 w3 = ((const float4*)(lw + (k + 3) * D_))[l];
            float4 u0 = ((const float4*)(lu + (rl + 0) * D_))[k4];
            float4 u1 = ((const float4*)(lu + (rl + 1) * D_))[k4];
            float4 u2 = ((const float4*)(lu + (rl + 2) * D_))[k4];
            float4 u3 = ((const float4*)(lu + (rl + 3) * D_))[k4];
            a0 = fma4(u0.x, w0, fma4(u0.y, w1, fma4(u0.z, w2, fma4(u0.w, w3, a0))));
            a1 = fma4(u1.x, w0, fma4(u1.y, w1, fma4(u1.z, w2, fma4(u1.w, w3, a1))));
            a2 = fma4(u2.x, w0, fma4(u2.y, w1, fma4(u2.z, w2, fma4(u2.w, w3, a2))));
            a3 = fma4(u3.x, w0, fma4(u3.y, w1, fma4(u3.z, w2, fma4(u3.w, w3, a3))));
        }
        float4 accs[4] = {a0, a1, a2, a3};
#pragma unroll
        for (int r = 0; r < 4; ++r) {
            int row = row0 + rl + r;
            if (row < N_) {
                float4 a = accs[r];
                float2 n2 = ((const float2*)noise)[(size_t)row * 32 + l];
                float z0 = (a.x + bb.x) + n2.x * expf(a.y + bb.y);
                float z1 = (a.z + bb.z) + n2.y * expf(a.w + bb.w);
                z[(size_t)row * 32 + l] =
                    (unsigned int)f2bf(z0) | ((unsigned int)f2bf(z1) << 16);
            }
        }
    }
}

// ---------------------------------------------------------------------------
// 6. Decoder: logits[e] = dot(z[src], z[dst]) over 64 bf16. 16 lanes per edge.
// ---------------------------------------------------------------------------
__global__ __launch_bounds__(256) void k_decode(const int* __restrict__ src,
                                                const int* __restrict__ dst,
                                                const unsigned int* __restrict__ z,
                                                float* __restrict__ out) {
    int e = blockIdx.x * 16 + (threadIdx.x >> 4);
    if (e >= E_) return;
    int l = threadIdx.x & 15;
    int s = src[e], d = dst[e];
    uint2 za = ((const uint2*)z)[(size_t)s * 16 + l];
    uint2 zb = ((const uint2*)z)[(size_t)d * 16 + l];
    float p = blo(za.x) * blo(zb.x) + bhi(za.x) * bhi(zb.x)
            + blo(za.y) * blo(zb.y) + bhi(za.y) * bhi(zb.y);
#pragma unroll
    for (int o = 8; o; o >>= 1) p += __shfl_xor(p, o);
    if (l == 0) out[e] = p;
}

// ---------------------------------------------------------------------------
extern "C" void kernel_launch(void* const* d_in, const int* in_sizes, int n_in,
                              void* d_out, int out_size, void* d_ws, size_t ws_size,
                              hipStream_t stream) {
    const int*   fi    = (const int*)d_in[0];
    const float* fw    = (const float*)d_in[2];
    const int*   ei    = (const int*)d_in[3];
    const float* noise = (const float*)d_in[4];
    const float* emb   = (const float*)d_in[5];
    const float* W1    = (const float*)d_in[6];
    const float* b1    = (const float*)d_in[7];
    const float* Wmu   = (const float*)d_in[8];
    const float* bmu   = (const float*)d_in[9];
    const float* Wls   = (const float*)d_in[10];
    const float* bls   = (const float*)d_in[11];
    float* out = (float*)d_out;

    const int* src = ei;
    const int* dst = ei + E_;

    // Workspace layout (4-byte units). The 25.6MB alias region serves, in
    // non-overlapping lifetime order: emb_bf (cvt->embed), binned (bin->fill2),
    // agg (gather->gemm).
    float*        ws        = (float*)d_ws;
    float*        agg       = ws;                                    // N*128 f32 = 25.6MB
    unsigned int* emb_bf    = (unsigned int*)agg;                    // V*64 u32 = 25.6MB
    unsigned int* binned    = (unsigned int*)agg;                    // E u32 = 6.4MB
    unsigned int* x         = (unsigned int*)(agg + (size_t)N_ * D_);// N*64 u32
    unsigned int* h         = x + (size_t)N_ * 64;                   // N*64 u32
    unsigned int* z         = h + (size_t)N_ * 64;                   // N*32 u32
    float*        disq      = (float*)(z + (size_t)N_ * 32);         // N
    float*        dinv      = disq + N_;                             // N
    int*          row_start = (int*)(dinv + N_);                     // N+1
    int*          sorted_src= row_start + (N_ + 1);                  // E
    int*          bin_total = sorted_src + E_;                       // 256
    int*          coarse_start  = bin_total + 256;                   // NBIN+1
    int*          coarse_cursor = coarse_start + 256;                // NBIN+1

    hipMemsetAsync(bin_total, 0, 256 * sizeof(int), stream);

    k_cvt    <<<(V_ * D_ / 8 + 255) / 256, 256, 0, stream>>>(emb, emb_bf);
    k_embed  <<<N_ / 4,                 256, 0, stream>>>(fi, fw, emb_bf, x);
    k_bhist  <<<(E_ + EPB_ - 1) / EPB_, 256, 0, stream>>>(dst, bin_total);
    k_scan196<<<1,                      256, 0, stream>>>(bin_total, coarse_start,
                                                          coarse_cursor, row_start);
    k_bin    <<<(E_ + EPB_ - 1) / EPB_, 256, 0, stream>>>(src, dst, coarse_cursor, binned);
    k_node   <<<NBIN_,                  256, 0, stream>>>(binned, coarse_start,
                                                          disq, dinv, row_start);
    k_fill2  <<<NBIN_,                  256, 0, stream>>>(binned, coarse_start,
                                                          row_start, sorted_src);

    // GCN layer 1
    k_gather   <<<N_ / 4, 256, 0, stream>>>(row_start, sorted_src, disq, dinv, x, agg);
    k_gemm_relu<<<512,    256, 0, stream>>>(agg, W1, b1, (unsigned short*)h);

    // GCN layers 2+3 (one gather of h, fused mu/ls GEMM)
    k_gather <<<N_ / 4,   256, 0, stream>>>(row_start, sorted_src, disq, dinv, h, agg);
    k_gemm_z <<<512,      256, 0, stream>>>(agg, Wmu, bmu, Wls, bls, noise, z);

    // Decoder
    k_decode <<<E_ / 16,  256, 0, stream>>>(src, dst, z, out);
}

// Round 8
// 449.337 us; speedup vs baseline: 1.5109x; 1.0901x over previous
//
#include <hip/hip_runtime.h>
#include <hip/hip_bf16.h>

// VGAE forward, MI355X. Gather-based GCN; bf16 storage for all gathered operands
// (x, h, z, agg). CSR build via two-level binned counting sort (LDS atomics only).
// Random-row kernels use wide loads (uint2/uint4) + multi-edge batching for MLP.
constexpr int N_ = 50000;
constexpr int E_ = 1600000;
constexpr int D_ = 128;   // embedding_dim == hidden_dim
constexpr int O_ = 64;    // out_embedding_dim
constexpr int NNZ_ = 16;
constexpr int V_ = 100000;
constexpr int NBIN_ = (N_ + 255) / 256;   // 196 coarse bins (dst>>8)

static __device__ __forceinline__ unsigned short f2bf(float f) {
    __hip_bfloat16 h = __float2bfloat16(f);
    return __builtin_bit_cast(unsigned short, h);
}
static __device__ __forceinline__ unsigned int pack2(float a, float b) {
    return (unsigned int)f2bf(a) | ((unsigned int)f2bf(b) << 16);
}
static __device__ __forceinline__ float blo(unsigned int u) { return __uint_as_float(u << 16); }
static __device__ __forceinline__ float bhi(unsigned int u) { return __uint_as_float(u & 0xffff0000u); }
static __device__ __forceinline__ float4 fma4(float s, float4 a, float4 b) {
    return make_float4(fmaf(s, a.x, b.x), fmaf(s, a.y, b.y),
                       fmaf(s, a.z, b.z), fmaf(s, a.w, b.w));
}

// ---------------------------------------------------------------------------
// 0. Convert fp32 emb table [V][128] -> bf16 (packed u32 pairs).
// ---------------------------------------------------------------------------
__global__ __launch_bounds__(256) void k_cvt(const float* __restrict__ emb,
                                             unsigned int* __restrict__ emb_bf) {
    int t = blockIdx.x * blockDim.x + threadIdx.x;
    if (t >= V_ * D_ / 8) return;
    float4 a = ((const float4*)emb)[t * 2];
    float4 b = ((const float4*)emb)[t * 2 + 1];
    uint4 o;
    o.x = pack2(a.x, a.y);
    o.y = pack2(a.z, a.w);
    o.z = pack2(b.x, b.y);
    o.w = pack2(b.z, b.w);
    ((uint4*)emb_bf)[t] = o;
}

// ---------------------------------------------------------------------------
// 1. EmbeddingBag(sum) + L2 normalize. Half-wave (32 lanes x uint2) per node,
//    2 nodes per wave -> half the load instructions of the u32 version.
// ---------------------------------------------------------------------------
__global__ __launch_bounds__(256) void k_embed(const int* __restrict__ fi,
                                               const float* __restrict__ fw,
                                               const unsigned int* __restrict__ emb_bf,
                                               unsigned int* __restrict__ x) {
    int lane = threadIdx.x & 63;
    int h = lane >> 5, c = lane & 31;
    int n = blockIdx.x * 8 + ((threadIdx.x >> 6) << 1) + h;
    if (n >= N_) return;
    float a0 = 0.f, a1 = 0.f, a2 = 0.f, a3 = 0.f;
    int base = n * NNZ_;
#pragma unroll
    for (int j = 0; j < NNZ_; ++j) {
        int idx  = fi[base + j];
        float w  = fw[base + j];
        uint2 r = ((const uint2*)emb_bf)[(size_t)idx * 32 + c];
        a0 = fmaf(w, blo(r.x), a0);
        a1 = fmaf(w, bhi(r.x), a1);
        a2 = fmaf(w, blo(r.y), a2);
        a3 = fmaf(w, bhi(r.y), a3);
    }
    float ss = a0 * a0 + a1 * a1 + a2 * a2 + a3 * a3;
#pragma unroll
    for (int o = 16; o; o >>= 1) ss += __shfl_xor(ss, o);
    float sc = 1.0f / fmaxf(sqrtf(ss), 1e-12f);
    ((uint2*)x)[(size_t)n * 32 + c] =
        make_uint2(pack2(a0 * sc, a1 * sc), pack2(a2 * sc, a3 * sc));
}

// ---------------------------------------------------------------------------
// 2a. Coarse-bin histogram of dst>>8: LDS hist per block, 196 global atomics.
// ---------------------------------------------------------------------------
constexpr int EPB_ = 4096;   // edges per block
__global__ __launch_bounds__(256) void k_bhist(const int* __restrict__ dst,
                                               int* __restrict__ bin_total) {
    __shared__ int hist[256];
    int t = threadIdx.x;
    hist[t] = 0;
    __syncthreads();
    int e0 = blockIdx.x * EPB_;
#pragma unroll
    for (int i = 0; i < EPB_ / 256; ++i) {
        int e = e0 + i * 256 + t;
        if (e < E_) atomicAdd(&hist[dst[e] >> 8], 1);
    }
    __syncthreads();
    if (t < NBIN_ && hist[t]) atomicAdd(&bin_total[t], hist[t]);
}

// ---------------------------------------------------------------------------
// 2b. Scan 196 bin counts -> coarse_start[197] (+ cursor copy); row_start[N]=E.
// ---------------------------------------------------------------------------
__global__ __launch_bounds__(256) void k_scan196(const int* __restrict__ bin_total,
                                                 int* __restrict__ coarse_start,
                                                 int* __restrict__ coarse_cursor,
                                                 int* __restrict__ row_start) {
    __shared__ int s[256];
    int t = threadIdx.x;
    int v = (t < NBIN_) ? bin_total[t] : 0;
    s[t] = v;
    __syncthreads();
    for (int o = 1; o < 256; o <<= 1) {
        int u = (t >= o) ? s[t - o] : 0;
        __syncthreads();
        s[t] += u;
        __syncthreads();
    }
    int excl = s[t] - v;
    if (t <= NBIN_) { coarse_start[t] = excl; coarse_cursor[t] = excl; }
    if (t == 0) row_start[N_] = E_;
}

// ---------------------------------------------------------------------------
// 2c. Coarse binning: LDS histogram + one global atomic per (block,bin) to
//     reserve space; edges written grouped by bin, packed src|dlow<<16 (u32).
// ---------------------------------------------------------------------------
__global__ __launch_bounds__(256) void k_bin(const int* __restrict__ src,
                                             const int* __restrict__ dst,
                                             int* __restrict__ coarse_cursor,
                                             unsigned int* __restrict__ binned) {
    __shared__ int hist[256], base[256];
    int t = threadIdx.x;
    int e0 = blockIdx.x * EPB_;
    hist[t] = 0;
    __syncthreads();
#pragma unroll
    for (int i = 0; i < EPB_ / 256; ++i) {
        int e = e0 + i * 256 + t;
        if (e < E_) atomicAdd(&hist[dst[e] >> 8], 1);
    }
    __syncthreads();
    if (t < NBIN_ && hist[t]) base[t] = atomicAdd(&coarse_cursor[t], hist[t]);
    __syncthreads();
#pragma unroll
    for (int i = 0; i < EPB_ / 256; ++i) {
        int e = e0 + i * 256 + t;
        if (e < E_) {
            int d = dst[e];
            int pos = atomicAdd(&base[d >> 8], 1);
            binned[pos] = (unsigned int)src[e] | ((unsigned int)(d & 255) << 16);
        }
    }
}

// ---------------------------------------------------------------------------
// 2d. Per-node degree (LDS hist of binned slice) -> disq, dinv, row_start.
// ---------------------------------------------------------------------------
__global__ __launch_bounds__(256) void k_node(const unsigned int* __restrict__ binned,
                                              const int* __restrict__ coarse_start,
                                              float* __restrict__ disq,
                                              float* __restrict__ dinv,
                                              int* __restrict__ row_start) {
    __shared__ int hist[256], s[256];
    int t = threadIdx.x;
    hist[t] = 0;
    __syncthreads();
    int beg = coarse_start[blockIdx.x], end = coarse_start[blockIdx.x + 1];
    for (int j = beg + t; j < end; j += 256)
        atomicAdd(&hist[(binned[j] >> 16) & 255], 1);
    __syncthreads();
    int v = hist[t];
    int n = (blockIdx.x << 8) + t;
    if (n < N_) {
        float deg = 1.0f + (float)v;
        disq[n] = rsqrtf(deg);
        dinv[n] = 1.0f / deg;
    }
    s[t] = v;
    __syncthreads();
    for (int o = 1; o < 256; o <<= 1) {
        int u = (t >= o) ? s[t - o] : 0;
        __syncthreads();
        s[t] += u;
        __syncthreads();
    }
    if (n < N_) row_start[n] = beg + (s[t] - v);
}

// ---------------------------------------------------------------------------
// 2e. Final fill: one block per coarse bin; cursors in LDS; writes land in a
//     ~32KB window (L2-resident, lines fill completely).
// ---------------------------------------------------------------------------
__global__ __launch_bounds__(256) void k_fill2(const unsigned int* __restrict__ binned,
                                               const int* __restrict__ coarse_start,
                                               const int* __restrict__ row_start,
                                               int* __restrict__ sorted_src) {
    __shared__ int cur[256];
    int t = threadIdx.x;
    int n0 = blockIdx.x << 8;
    if (n0 + t < N_) cur[t] = row_start[n0 + t];
    __syncthreads();
    int beg = coarse_start[blockIdx.x], end = coarse_start[blockIdx.x + 1];
    for (int j = beg + t; j < end; j += 256) {
        unsigned int b = binned[j];
        int pos = atomicAdd(&cur[(b >> 16) & 255], 1);
        sorted_src[pos] = (int)(b & 0xFFFFu);
    }
}

// ---------------------------------------------------------------------------
// 3. Gather aggregation from bf16 rows -> bf16 agg.
//    agg[n] = disq[n] * sum_j disq[s_j]*v[s_j]  +  dinv[n]*v[n]
//    Wave per node; half-wave (32 lanes x uint2) per edge -> each load inst
//    fetches two 256B rows (2 edges). Cross-half shfl_xor(32) combine.
// ---------------------------------------------------------------------------
__global__ __launch_bounds__(256) void k_gather(const int* __restrict__ row_start,
                                                const int* __restrict__ sorted_src,
                                                const float* __restrict__ disq,
                                                const float* __restrict__ dinv,
                                                const unsigned int* __restrict__ v,
                                                unsigned int* __restrict__ agg) {
    int n = blockIdx.x * 4 + (threadIdx.x >> 6);
    if (n >= N_) return;
    int lane = threadIdx.x & 63;
    int h = lane >> 5, c = lane & 31;
    const uint2* V = (const uint2*)v;
    int beg = row_start[n], end = row_start[n + 1];
    float a0 = 0.f, a1 = 0.f, a2 = 0.f, a3 = 0.f;
    int j = beg;
    for (; j + 7 < end; j += 8) {
        int s0 = sorted_src[j     + h], s1 = sorted_src[j + 2 + h];
        int s2 = sorted_src[j + 4 + h], s3 = sorted_src[j + 6 + h];
        float w0 = disq[s0], w1 = disq[s1], w2 = disq[s2], w3 = disq[s3];
        uint2 b0 = V[(size_t)s0 * 32 + c];
        uint2 b1 = V[(size_t)s1 * 32 + c];
        uint2 b2 = V[(size_t)s2 * 32 + c];
        uint2 b3 = V[(size_t)s3 * 32 + c];
        a0 = fmaf(w0, blo(b0.x), a0); a1 = fmaf(w0, bhi(b0.x), a1);
        a2 = fmaf(w0, blo(b0.y), a2); a3 = fmaf(w0, bhi(b0.y), a3);
        a0 = fmaf(w1, blo(b1.x), a0); a1 = fmaf(w1, bhi(b1.x), a1);
        a2 = fmaf(w1, blo(b1.y), a2); a3 = fmaf(w1, bhi(b1.y), a3);
        a0 = fmaf(w2, blo(b2.x), a0); a1 = fmaf(w2, bhi(b2.x), a1);
        a2 = fmaf(w2, blo(b2.y), a2); a3 = fmaf(w2, bhi(b2.y), a3);
        a0 = fmaf(w3, blo(b3.x), a0); a1 = fmaf(w3, bhi(b3.x), a1);
        a2 = fmaf(w3, blo(b3.y), a2); a3 = fmaf(w3, bhi(b3.y), a3);
    }
    for (; j + h < end; j += 2) {
        int s = sorted_src[j + h];
        float w = disq[s];
        uint2 b = V[(size_t)s * 32 + c];
        a0 = fmaf(w, blo(b.x), a0); a1 = fmaf(w, bhi(b.x), a1);
        a2 = fmaf(w, blo(b.y), a2); a3 = fmaf(w, bhi(b.y), a3);
    }
    a0 += __shfl_xor(a0, 32); a1 += __shfl_xor(a1, 32);
    a2 += __shfl_xor(a2, 32); a3 += __shfl_xor(a3, 32);
    if (h == 0) {
        float dq = disq[n], di = dinv[n];
        uint2 bs = V[(size_t)n * 32 + c];
        a0 = fmaf(di, blo(bs.x), a0 * dq);
        a1 = fmaf(di, bhi(bs.x), a1 * dq);
        a2 = fmaf(di, blo(bs.y), a2 * dq);
        a3 = fmaf(di, bhi(bs.y), a3 * dq);
        ((uint2*)agg)[(size_t)n * 32 + c] = make_uint2(pack2(a0, a1), pack2(a2, a3));
    }
}

// ---------------------------------------------------------------------------
// 4. Register-blocked GEMM: h = relu(agg @ W1 + b1), bf16 in (unpack to f32
//    LDS), bf16 out. f32 accumulate.
// ---------------------------------------------------------------------------
__global__ __launch_bounds__(256, 2) void k_gemm_relu(const unsigned int* __restrict__ ub,
                                                      const float* __restrict__ W,
                                                      const float* __restrict__ b,
                                                      unsigned short* __restrict__ hout) {
    __shared__ float lw[D_ * D_];     // 64 KiB
    __shared__ float lu[32 * D_];     // 16 KiB
    int tid = threadIdx.x;
    for (int t = tid; t < D_ * D_ / 4; t += 256)
        ((float4*)lw)[t] = ((const float4*)W)[t];

    int l  = tid & 31;
    int rl = ((tid >> 6) << 3) + (((tid >> 5) & 1) << 2);
    float4 bb = ((const float4*)b)[l];

    for (int tile = blockIdx.x; tile * 32 < N_; tile += gridDim.x) {
        int row0 = tile * 32;
        __syncthreads();
#pragma unroll
        for (int i = 0; i < 8; ++i) {
            int t = i * 256 + tid;              // 0..2047 u32 slots
            int r = t >> 6, slot = t & 63;
            int gr = row0 + r;
            unsigned int bv = (gr < N_) ? ub[(size_t)gr * 64 + slot] : 0u;
            lu[r * D_ + slot * 2]     = blo(bv);
            lu[r * D_ + slot * 2 + 1] = bhi(bv);
        }
        __syncthreads();
        float4 a0 = {0,0,0,0}, a1 = {0,0,0,0}, a2 = {0,0,0,0}, a3 = {0,0,0,0};
#pragma unroll 4
        for (int k4 = 0; k4 < 32; ++k4) {
            int k = k4 * 4;
            float4 w0 = ((const float4*)(lw + (k + 0) * D_))[l];
            float4 w1 = ((const float4*)(lw + (k + 1) * D_))[l];
            float4 w2 = ((const float4*)(lw + (k + 2) * D_))[l];
            float4 w3 = ((const float4*)(lw + (k + 3) * D_))[l];
            float4 u0 = ((const float4*)(lu + (rl + 0) * D_))[k4];
            float4 u1 = ((const float4*)(lu + (rl + 1) * D_))[k4];
            float4 u2 = ((const float4*)(lu + (rl + 2) * D_))[k4];
            float4 u3 = ((const float4*)(lu + (rl + 3) * D_))[k4];
            a0 = fma4(u0.x, w0, fma4(u0.y, w1, fma4(u0.z, w2, fma4(u0.w, w3, a0))));
            a1 = fma4(u1.x, w0, fma4(u1.y, w1, fma4(u1.z, w2, fma4(u1.w, w3, a1))));
            a2 = fma4(u2.x, w0, fma4(u2.y, w1, fma4(u2.z, w2, fma4(u2.w, w3, a2))));
            a3 = fma4(u3.x, w0, fma4(u3.y, w1, fma4(u3.z, w2, fma4(u3.w, w3, a3))));
        }
        float4 accs[4] = {a0, a1, a2, a3};
#pragma unroll
        for (int r = 0; r < 4; ++r) {
            int row = row0 + rl + r;
            if (row < N_) {
                float4 a = accs[r];
                ushort4 o;
                o.x = f2bf(fmaxf(a.x + bb.x, 0.f));
                o.y = f2bf(fmaxf(a.y + bb.y, 0.f));
                o.z = f2bf(fmaxf(a.z + bb.z, 0.f));
                o.w = f2bf(fmaxf(a.w + bb.w, 0.f));
                ((ushort4*)hout)[(size_t)row * 32 + l] = o;
            }
        }
    }
}

// ---------------------------------------------------------------------------
// 5. Fused mu/logstd GEMM (columns interleaved); z = mu + noise*exp(ls), bf16.
// ---------------------------------------------------------------------------
__global__ __launch_bounds__(256, 2) void k_gemm_z(const unsigned int* __restrict__ gb,
                                                   const float* __restrict__ Wmu,
                                                   const float* __restrict__ bmu,
                                                   const float* __restrict__ Wls,
                                                   const float* __restrict__ bls,
                                                   const float* __restrict__ noise,
                                                   unsigned int* __restrict__ z) {
    __shared__ float lw[D_ * D_];     // 64 KiB (interleaved Wmu|Wls)
    __shared__ float lu[32 * D_];     // 16 KiB
    int tid = threadIdx.x;
    for (int t = tid; t < D_ * 32; t += 256) {
        int k = t >> 5, j2 = t & 31;
        float2 m2 = ((const float2*)Wmu)[k * 32 + j2];
        float2 l2 = ((const float2*)Wls)[k * 32 + j2];
        ((float4*)lw)[t] = make_float4(m2.x, l2.x, m2.y, l2.y);
    }

    int l  = tid & 31;
    int rl = ((tid >> 6) << 3) + (((tid >> 5) & 1) << 2);
    float2 bm = ((const float2*)bmu)[l];
    float2 bl = ((const float2*)bls)[l];
    float4 bb = make_float4(bm.x, bl.x, bm.y, bl.y);

    for (int tile = blockIdx.x; tile * 32 < N_; tile += gridDim.x) {
        int row0 = tile * 32;
        __syncthreads();
#pragma unroll
        for (int i = 0; i < 8; ++i) {
            int t = i * 256 + tid;
            int r = t >> 6, slot = t & 63;
            int gr = row0 + r;
            unsigned int bv = (gr < N_) ? gb[(size_t)gr * 64 + slot] : 0u;
            lu[r * D_ + slot * 2]     = blo(bv);
            lu[r * D_ + slot * 2 + 1] = bhi(bv);
        }
        __syncthreads();
        float4 a0 = {0,0,0,0}, a1 = {0,0,0,0}, a2 = {0,0,0,0}, a3 = {0,0,0,0};
#pragma unroll 4
        for (int k4 = 0; k4 < 32; ++k4) {
            int k = k4 * 4;
            float4 w0 = ((const float4*)(lw + (k + 0) * D_))[l];
            float4 w1 = ((const float4*)(lw + (k + 1) * D_))[l];
            float4 w2 = ((const float4*)(lw + (k + 2) * D_))[l];
            float4 w3 = ((const float4*)(lw + (k + 3) * D_))[l];
            float4 u0 = ((const float4*)(lu + (rl + 0) * D_))[k4];
            float4 u1 = ((const float4*)(lu + (rl + 1) * D_))[k4];
            float4 u2 = ((const float4*)(lu + (rl + 2) * D_))[k4];
            float4 u3 = ((const float4*)(lu + (rl + 3) * D_))[k4];
            a0 = fma4(u0.x, w0, fma4(u0.y, w1, fma4(u0.z, w2, fma4(u0.w, w3, a0))));
            a1 = fma4(u1.x, w0, fma4(u1.y, w1, fma4(u1.z, w2, fma4(u1.w, w3, a1))));
            a2 = fma4(u2.x, w0, fma4(u2.y, w1, fma4(u2.z, w2, fma4(u2.w, w3, a2))));
            a3 = fma4(u3.x, w0, fma4(u3.y, w1, fma4(u3.z, w2, fma4(u3.w, w3, a3))));
        }
        float4 accs[4] = {a0, a1, a2, a3};
#pragma unroll
        for (int r = 0; r < 4; ++r) {
            int row = row0 + rl + r;
            if (row < N_) {
                float4 a = accs[r];
                float2 n2 = ((const float2*)noise)[(size_t)row * 32 + l];
                float z0 = (a.x + bb.x) + n2.x * expf(a.y + bb.y);
                float z1 = (a.z + bb.z) + n2.y * expf(a.w + bb.w);
                z[(size_t)row * 32 + l] = pack2(z0, z1);
            }
        }
    }
}

// ---------------------------------------------------------------------------
// 6. Decoder: logits[e] = dot(z[src], z[dst]) over 64 bf16.
//    8 lanes x uint4 per row; 2 edges batched per group -> 4 loads in flight.
// ---------------------------------------------------------------------------
__global__ __launch_bounds__(256) void k_decode(const int* __restrict__ src,
                                                const int* __restrict__ dst,
                                                const unsigned int* __restrict__ z,
                                                float* __restrict__ out) {
    int l = threadIdx.x & 7;
    int e0 = blockIdx.x * 64 + ((threadIdx.x >> 3) << 1);   // E_ % 64 == 0
    int s0 = src[e0], d0 = dst[e0];
    int s1 = src[e0 + 1], d1 = dst[e0 + 1];
    const uint4* Z = (const uint4*)z;
    uint4 za0 = Z[(size_t)s0 * 8 + l];
    uint4 zb0 = Z[(size_t)d0 * 8 + l];
    uint4 za1 = Z[(size_t)s1 * 8 + l];
    uint4 zb1 = Z[(size_t)d1 * 8 + l];
    float p0 = blo(za0.x) * blo(zb0.x) + bhi(za0.x) * bhi(zb0.x)
             + blo(za0.y) * blo(zb0.y) + bhi(za0.y) * bhi(zb0.y)
             + blo(za0.z) * blo(zb0.z) + bhi(za0.z) * bhi(zb0.z)
             + blo(za0.w) * blo(zb0.w) + bhi(za0.w) * bhi(zb0.w);
    float p1 = blo(za1.x) * blo(zb1.x) + bhi(za1.x) * bhi(zb1.x)
             + blo(za1.y) * blo(zb1.y) + bhi(za1.y) * bhi(zb1.y)
             + blo(za1.z) * blo(zb1.z) + bhi(za1.z) * bhi(zb1.z)
             + blo(za1.w) * blo(zb1.w) + bhi(za1.w) * bhi(zb1.w);
#pragma unroll
    for (int o = 4; o; o >>= 1) {
        p0 += __shfl_xor(p0, o);
        p1 += __shfl_xor(p1, o);
    }
    if (l == 0) {
        out[e0]     = p0;
        out[e0 + 1] = p1;
    }
}

// ---------------------------------------------------------------------------
extern "C" void kernel_launch(void* const* d_in, const int* in_sizes, int n_in,
                              void* d_out, int out_size, void* d_ws, size_t ws_size,
                              hipStream_t stream) {
    const int*   fi    = (const int*)d_in[0];
    const float* fw    = (const float*)d_in[2];
    const int*   ei    = (const int*)d_in[3];
    const float* noise = (const float*)d_in[4];
    const float* emb   = (const float*)d_in[5];
    const float* W1    = (const float*)d_in[6];
    const float* b1    = (const float*)d_in[7];
    const float* Wmu   = (const float*)d_in[8];
    const float* bmu   = (const float*)d_in[9];
    const float* Wls   = (const float*)d_in[10];
    const float* bls   = (const float*)d_in[11];
    float* out = (float*)d_out;

    const int* src = ei;
    const int* dst = ei + E_;

    // Workspace layout (4-byte units). The 25.6MB alias region serves, in
    // non-overlapping lifetime order: emb_bf (cvt->embed), binned (bin->fill2),
    // agg bf16 (gather->gemm; uses first 12.8MB).
    float*        ws        = (float*)d_ws;
    unsigned int* aggb      = (unsigned int*)ws;                     // N*64 u32 = 12.8MB
    unsigned int* emb_bf    = (unsigned int*)ws;                     // V*64 u32 = 25.6MB
    unsigned int* binned    = (unsigned int*)ws;                     // E u32 = 6.4MB
    unsigned int* x         = (unsigned int*)ws + (size_t)V_ * 64;   // N*64 u32
    unsigned int* h         = x + (size_t)N_ * 64;                   // N*64 u32
    unsigned int* z         = h + (size_t)N_ * 64;                   // N*32 u32
    float*        disq      = (float*)(z + (size_t)N_ * 32);         // N
    float*        dinv      = disq + N_;                             // N
    int*          row_start = (int*)(dinv + N_);                     // N+1
    int*          sorted_src= row_start + (N_ + 1);                  // E
    int*          bin_total = sorted_src + E_;                       // 256
    int*          coarse_start  = bin_total + 256;                   // NBIN+1
    int*          coarse_cursor = coarse_start + 256;                // NBIN+1

    hipMemsetAsync(bin_total, 0, 256 * sizeof(int), stream);

    k_cvt    <<<(V_ * D_ / 8 + 255) / 256, 256, 0, stream>>>(emb, emb_bf);
    k_embed  <<<(N_ + 7) / 8,           256, 0, stream>>>(fi, fw, emb_bf, x);
    k_bhist  <<<(E_ + EPB_ - 1) / EPB_, 256, 0, stream>>>(dst, bin_total);
    k_scan196<<<1,                      256, 0, stream>>>(bin_total, coarse_start,
                                                          coarse_cursor, row_start);
    k_bin    <<<(E_ + EPB_ - 1) / EPB_, 256, 0, stream>>>(src, dst, coarse_cursor, binned);
    k_node   <<<NBIN_,                  256, 0, stream>>>(binned, coarse_start,
                                                          disq, dinv, row_start);
    k_fill2  <<<NBIN_,                  256, 0, stream>>>(binned, coarse_start,
                                                          row_start, sorted_src);

    // GCN layer 1
    k_gather   <<<N_ / 4, 256, 0, stream>>>(row_start, sorted_src, disq, dinv, x, aggb);
    k_gemm_relu<<<512,    256, 0, stream>>>(aggb, W1, b1, (unsigned short*)h);

    // GCN layers 2+3 (one gather of h, fused mu/ls GEMM)
    k_gather <<<N_ / 4,   256, 0, stream>>>(row_start, sorted_src, disq, dinv, h, aggb);
    k_gemm_z <<<512,      256, 0, stream>>>(aggb, Wmu, bmu, Wls, bls, noise, z);

    // Decoder
    k_decode <<<E_ / 64,  256, 0, stream>>>(src, dst, z, out);
}

// Round 10
// 444.951 us; speedup vs baseline: 1.5258x; 1.0099x over previous
//
#include <hip/hip_runtime.h>
#include <hip/hip_bf16.h>

// VGAE forward, MI355X. Gather-based GCN; bf16 storage for all gathered operands
// (x, h, z, agg). CSR build via two-level binned counting sort (LDS atomics only).
// Random-row kernels: full-row uint4 loads, multi-edge batching for deep MLP.
constexpr int N_ = 50000;
constexpr int E_ = 1600000;
constexpr int D_ = 128;   // embedding_dim == hidden_dim
constexpr int O_ = 64;    // out_embedding_dim
constexpr int NNZ_ = 16;
constexpr int V_ = 100000;
constexpr int NBIN_ = (N_ + 255) / 256;   // 196 coarse bins (dst>>8)

static __device__ __forceinline__ unsigned short f2bf(float f) {
    __hip_bfloat16 h = __float2bfloat16(f);
    return __builtin_bit_cast(unsigned short, h);
}
static __device__ __forceinline__ unsigned int pack2(float a, float b) {
    return (unsigned int)f2bf(a) | ((unsigned int)f2bf(b) << 16);
}
static __device__ __forceinline__ float blo(unsigned int u) { return __uint_as_float(u << 16); }
static __device__ __forceinline__ float bhi(unsigned int u) { return __uint_as_float(u & 0xffff0000u); }
static __device__ __forceinline__ float4 fma4(float s, float4 a, float4 b) {
    return make_float4(fmaf(s, a.x, b.x), fmaf(s, a.y, b.y),
                       fmaf(s, a.z, b.z), fmaf(s, a.w, b.w));
}

// ---------------------------------------------------------------------------
// 0. Convert fp32 emb table [V][128] -> bf16 (packed u32 pairs).
// ---------------------------------------------------------------------------
__global__ __launch_bounds__(256) void k_cvt(const float* __restrict__ emb,
                                             unsigned int* __restrict__ emb_bf) {
    int t = blockIdx.x * blockDim.x + threadIdx.x;
    if (t >= V_ * D_ / 8) return;
    float4 a = ((const float4*)emb)[t * 2];
    float4 b = ((const float4*)emb)[t * 2 + 1];
    uint4 o;
    o.x = pack2(a.x, a.y);
    o.y = pack2(a.z, a.w);
    o.z = pack2(b.x, b.y);
    o.w = pack2(b.z, b.w);
    ((uint4*)emb_bf)[t] = o;
}

// ---------------------------------------------------------------------------
// 1. EmbeddingBag(sum) + L2 normalize. Half-wave (32 lanes x uint2) per node,
//    2 nodes per wave.
// ---------------------------------------------------------------------------
__global__ __launch_bounds__(256) void k_embed(const int* __restrict__ fi,
                                               const float* __restrict__ fw,
                                               const unsigned int* __restrict__ emb_bf,
                                               unsigned int* __restrict__ x) {
    int lane = threadIdx.x & 63;
    int h = lane >> 5, c = lane & 31;
    int n = blockIdx.x * 8 + ((threadIdx.x >> 6) << 1) + h;
    if (n >= N_) return;
    float a0 = 0.f, a1 = 0.f, a2 = 0.f, a3 = 0.f;
    int base = n * NNZ_;
#pragma unroll
    for (int j = 0; j < NNZ_; ++j) {
        int idx  = fi[base + j];
        float w  = fw[base + j];
        uint2 r = ((const uint2*)emb_bf)[(size_t)idx * 32 + c];
        a0 = fmaf(w, blo(r.x), a0);
        a1 = fmaf(w, bhi(r.x), a1);
        a2 = fmaf(w, blo(r.y), a2);
        a3 = fmaf(w, bhi(r.y), a3);
    }
    float ss = a0 * a0 + a1 * a1 + a2 * a2 + a3 * a3;
#pragma unroll
    for (int o = 16; o; o >>= 1) ss += __shfl_xor(ss, o);
    float sc = 1.0f / fmaxf(sqrtf(ss), 1e-12f);
    ((uint2*)x)[(size_t)n * 32 + c] =
        make_uint2(pack2(a0 * sc, a1 * sc), pack2(a2 * sc, a3 * sc));
}

// ---------------------------------------------------------------------------
// 2a. Coarse-bin histogram of dst>>8: LDS hist per block, 196 global atomics.
// ---------------------------------------------------------------------------
constexpr int EPB_ = 8192;   // edges per block
__global__ __launch_bounds__(256) void k_bhist(const int* __restrict__ dst,
                                               int* __restrict__ bin_total) {
    __shared__ int hist[256];
    int t = threadIdx.x;
    hist[t] = 0;
    __syncthreads();
    int e0 = blockIdx.x * EPB_;
#pragma unroll
    for (int i = 0; i < EPB_ / 256; ++i) {
        int e = e0 + i * 256 + t;
        if (e < E_) atomicAdd(&hist[dst[e] >> 8], 1);
    }
    __syncthreads();
    if (t < NBIN_ && hist[t]) atomicAdd(&bin_total[t], hist[t]);
}

// ---------------------------------------------------------------------------
// 2b. Scan 196 bin counts -> coarse_start[197] (+ cursor copy); row_start[N]=E.
// ---------------------------------------------------------------------------
__global__ __launch_bounds__(256) void k_scan196(const int* __restrict__ bin_total,
                                                 int* __restrict__ coarse_start,
                                                 int* __restrict__ coarse_cursor,
                                                 int* __restrict__ row_start) {
    __shared__ int s[256];
    int t = threadIdx.x;
    int v = (t < NBIN_) ? bin_total[t] : 0;
    s[t] = v;
    __syncthreads();
    for (int o = 1; o < 256; o <<= 1) {
        int u = (t >= o) ? s[t - o] : 0;
        __syncthreads();
        s[t] += u;
        __syncthreads();
    }
    int excl = s[t] - v;
    if (t <= NBIN_) { coarse_start[t] = excl; coarse_cursor[t] = excl; }
    if (t == 0) row_start[N_] = E_;
}

// ---------------------------------------------------------------------------
// 2c. Coarse binning: LDS histogram + one global atomic per (block,bin) to
//     reserve space; edges written grouped by bin, packed src|dlow<<16 (u32).
// ---------------------------------------------------------------------------
__global__ __launch_bounds__(256) void k_bin(const int* __restrict__ src,
                                             const int* __restrict__ dst,
                                             int* __restrict__ coarse_cursor,
                                             unsigned int* __restrict__ binned) {
    __shared__ int hist[256], base[256];
    int t = threadIdx.x;
    int e0 = blockIdx.x * EPB_;
    hist[t] = 0;
    __syncthreads();
#pragma unroll
    for (int i = 0; i < EPB_ / 256; ++i) {
        int e = e0 + i * 256 + t;
        if (e < E_) atomicAdd(&hist[dst[e] >> 8], 1);
    }
    __syncthreads();
    if (t < NBIN_ && hist[t]) base[t] = atomicAdd(&coarse_cursor[t], hist[t]);
    __syncthreads();
#pragma unroll
    for (int i = 0; i < EPB_ / 256; ++i) {
        int e = e0 + i * 256 + t;
        if (e < E_) {
            int d = dst[e];
            int pos = atomicAdd(&base[d >> 8], 1);
            binned[pos] = (unsigned int)src[e] | ((unsigned int)(d & 255) << 16);
        }
    }
}

// ---------------------------------------------------------------------------
// 2d. Per-node degree (LDS hist of binned slice) -> disq, dinv, row_start.
// ---------------------------------------------------------------------------
__global__ __launch_bounds__(256) void k_node(const unsigned int* __restrict__ binned,
                                              const int* __restrict__ coarse_start,
                                              float* __restrict__ disq,
                                              float* __restrict__ dinv,
                                              int* __restrict__ row_start) {
    __shared__ int hist[256], s[256];
    int t = threadIdx.x;
    hist[t] = 0;
    __syncthreads();
    int beg = coarse_start[blockIdx.x], end = coarse_start[blockIdx.x + 1];
    for (int j = beg + t; j < end; j += 256)
        atomicAdd(&hist[(binned[j] >> 16) & 255], 1);
    __syncthreads();
    int v = hist[t];
    int n = (blockIdx.x << 8) + t;
    if (n < N_) {
        float deg = 1.0f + (float)v;
        disq[n] = rsqrtf(deg);
        dinv[n] = 1.0f / deg;
    }
    s[t] = v;
    __syncthreads();
    for (int o = 1; o < 256; o <<= 1) {
        int u = (t >= o) ? s[t - o] : 0;
        __syncthreads();
        s[t] += u;
        __syncthreads();
    }
    if (n < N_) row_start[n] = beg + (s[t] - v);
}

// ---------------------------------------------------------------------------
// 2e. Final fill: one block per coarse bin; cursors in LDS; writes land in a
//     ~32KB window (L2-resident, lines fill completely).
// ---------------------------------------------------------------------------
__global__ __launch_bounds__(256) void k_fill2(const unsigned int* __restrict__ binned,
                                               const int* __restrict__ coarse_start,
                                               const int* __restrict__ row_start,
                                               int* __restrict__ sorted_src) {
    __shared__ int cur[256];
    int t = threadIdx.x;
    int n0 = blockIdx.x << 8;
    if (n0 + t < N_) cur[t] = row_start[n0 + t];
    __syncthreads();
    int beg = coarse_start[blockIdx.x], end = coarse_start[blockIdx.x + 1];
    for (int j = beg + t; j < end; j += 256) {
        unsigned int b = binned[j];
        int pos = atomicAdd(&cur[(b >> 16) & 255], 1);
        sorted_src[pos] = (int)(b & 0xFFFFu);
    }
}

// ---------------------------------------------------------------------------
// 3. Gather aggregation from bf16 rows -> bf16 agg.
//    agg[n] = disq[n] * sum_j disq[s_j]*v[s_j]  +  dinv[n]*v[n]
//    Wave per node; quarter-wave (16 lanes x uint4) per edge: ONE wave-load
//    instruction = one full 256B row, 4 edges concurrent, 16-edge unroll
//    -> 4 x 16B loads in flight per lane. Cross-group shfl_xor(16,32) reduce.
// ---------------------------------------------------------------------------
__global__ __launch_bounds__(256) void k_gather(const int* __restrict__ row_start,
                                                const int* __restrict__ sorted_src,
                                                const float* __restrict__ disq,
                                                const float* __restrict__ dinv,
                                                const unsigned int* __restrict__ v,
                                                unsigned int* __restrict__ agg) {
    int n = blockIdx.x * 4 + (threadIdx.x >> 6);
    if (n >= N_) return;
    int lane = threadIdx.x & 63;
    int g = lane >> 4, c = lane & 15;           // group 0..3, col 0..15
    const uint4* V = (const uint4*)v;           // row = 16 uint4 = 256B
    int beg = row_start[n], end = row_start[n + 1];
    float a0 = 0.f, a1 = 0.f, a2 = 0.f, a3 = 0.f;
    float a4 = 0.f, a5 = 0.f, a6 = 0.f, a7 = 0.f;
    int j = beg;
    for (; j + 15 < end; j += 16) {
        int s0 = sorted_src[j      + g];
        int s1 = sorted_src[j + 4  + g];
        int s2 = sorted_src[j + 8  + g];
        int s3 = sorted_src[j + 12 + g];
        float w0 = disq[s0], w1 = disq[s1], w2 = disq[s2], w3 = disq[s3];
        uint4 b0 = V[(size_t)s0 * 16 + c];
        uint4 b1 = V[(size_t)s1 * 16 + c];
        uint4 b2 = V[(size_t)s2 * 16 + c];
        uint4 b3 = V[(size_t)s3 * 16 + c];
        a0 = fmaf(w0, blo(b0.x), a0); a1 = fmaf(w0, bhi(b0.x), a1);
        a2 = fmaf(w0, blo(b0.y), a2); a3 = fmaf(w0, bhi(b0.y), a3);
        a4 = fmaf(w0, blo(b0.z), a4); a5 = fmaf(w0, bhi(b0.z), a5);
        a6 = fmaf(w0, blo(b0.w), a6); a7 = fmaf(w0, bhi(b0.w), a7);
        a0 = fmaf(w1, blo(b1.x), a0); a1 = fmaf(w1, bhi(b1.x), a1);
        a2 = fmaf(w1, blo(b1.y), a2); a3 = fmaf(w1, bhi(b1.y), a3);
        a4 = fmaf(w1, blo(b1.z), a4); a5 = fmaf(w1, bhi(b1.z), a5);
        a6 = fmaf(w1, blo(b1.w), a6); a7 = fmaf(w1, bhi(b1.w), a7);
        a0 = fmaf(w2, blo(b2.x), a0); a1 = fmaf(w2, bhi(b2.x), a1);
        a2 = fmaf(w2, blo(b2.y), a2); a3 = fmaf(w2, bhi(b2.y), a3);
        a4 = fmaf(w2, blo(b2.z), a4); a5 = fmaf(w2, bhi(b2.z), a5);
        a6 = fmaf(w2, blo(b2.w), a6); a7 = fmaf(w2, bhi(b2.w), a7);
        a0 = fmaf(w3, blo(b3.x), a0); a1 = fmaf(w3, bhi(b3.x), a1);
        a2 = fmaf(w3, blo(b3.y), a2); a3 = fmaf(w3, bhi(b3.y), a3);
        a4 = fmaf(w3, blo(b3.z), a4); a5 = fmaf(w3, bhi(b3.z), a5);
        a6 = fmaf(w3, blo(b3.w), a6); a7 = fmaf(w3, bhi(b3.w), a7);
    }
    for (; j + g < end; j += 4) {
        int s = sorted_src[j + g];
        float w = disq[s];
        uint4 b = V[(size_t)s * 16 + c];
        a0 = fmaf(w, blo(b.x), a0); a1 = fmaf(w, bhi(b.x), a1);
        a2 = fmaf(w, blo(b.y), a2); a3 = fmaf(w, bhi(b.y), a3);
        a4 = fmaf(w, blo(b.z), a4); a5 = fmaf(w, bhi(b.z), a5);
        a6 = fmaf(w, blo(b.w), a6); a7 = fmaf(w, bhi(b.w), a7);
    }
    a0 += __shfl_xor(a0, 16); a0 += __shfl_xor(a0, 32);
    a1 += __shfl_xor(a1, 16); a1 += __shfl_xor(a1, 32);
    a2 += __shfl_xor(a2, 16); a2 += __shfl_xor(a2, 32);
    a3 += __shfl_xor(a3, 16); a3 += __shfl_xor(a3, 32);
    a4 += __shfl_xor(a4, 16); a4 += __shfl_xor(a4, 32);
    a5 += __shfl_xor(a5, 16); a5 += __shfl_xor(a5, 32);
    a6 += __shfl_xor(a6, 16); a6 += __shfl_xor(a6, 32);
    a7 += __shfl_xor(a7, 16); a7 += __shfl_xor(a7, 32);
    if (g == 0) {
        float dq = disq[n], di = dinv[n];
        uint4 bs = V[(size_t)n * 16 + c];
        a0 = fmaf(di, blo(bs.x), a0 * dq); a1 = fmaf(di, bhi(bs.x), a1 * dq);
        a2 = fmaf(di, blo(bs.y), a2 * dq); a3 = fmaf(di, bhi(bs.y), a3 * dq);
        a4 = fmaf(di, blo(bs.z), a4 * dq); a5 = fmaf(di, bhi(bs.z), a5 * dq);
        a6 = fmaf(di, blo(bs.w), a6 * dq); a7 = fmaf(di, bhi(bs.w), a7 * dq);
        ((uint4*)agg)[(size_t)n * 16 + c] =
            make_uint4(pack2(a0, a1), pack2(a2, a3), pack2(a4, a5), pack2(a6, a7));
    }
}

// ---------------------------------------------------------------------------
// 4. Register-blocked GEMM: h = relu(agg @ W1 + b1), bf16 in (unpack to f32
//    LDS), bf16 out. f32 accumulate.
// ---------------------------------------------------------------------------
__global__ __launch_bounds__(256, 2) void k_gemm_relu(const unsigned int* __restrict__ ub,
                                                      const float* __restrict__ W,
                                                      const float* __restrict__ b,
                                                      unsigned short* __restrict__ hout) {
    __shared__ float lw[D_ * D_];     // 64 KiB
    __shared__ float lu[32 * D_];     // 16 KiB
    int tid = threadIdx.x;
    for (int t = tid; t < D_ * D_ / 4; t += 256)
        ((float4*)lw)[t] = ((const float4*)W)[t];

    int l  = tid & 31;
    int rl = ((tid >> 6) << 3) + (((tid >> 5) & 1) << 2);
    float4 bb = ((const float4*)b)[l];

    for (int tile = blockIdx.x; tile * 32 < N_; tile += gridDim.x) {
        int row0 = tile * 32;
        __syncthreads();
#pragma unroll
        for (int i = 0; i < 8; ++i) {
            int t = i * 256 + tid;              // 0..2047 u32 slots
            int r = t >> 6, slot = t & 63;
            int gr = row0 + r;
            unsigned int bv = (gr < N_) ? ub[(size_t)gr * 64 + slot] : 0u;
            lu[r * D_ + slot * 2]     = blo(bv);
            lu[r * D_ + slot * 2 + 1] = bhi(bv);
        }
        __syncthreads();
        float4 a0 = {0,0,0,0}, a1 = {0,0,0,0}, a2 = {0,0,0,0}, a3 = {0,0,0,0};
#pragma unroll 4
        for (int k4 = 0; k4 < 32; ++k4) {
            int k = k4 * 4;
            float4 w0 = ((const float4*)(lw + (k + 0) * D_))[l];
            float4 w1 = ((const float4*)(lw + (k + 1) * D_))[l];
            float4 w2 = ((const float4*)(lw + (k + 2) * D_))[l];
            float4 w3 = ((const float4*)(lw + (k + 3) * D_))[l];
            float4 u0 = ((const float4*)(lu + (rl + 0) * D_))[k4];
            float4 u1 = ((const float4*)(lu + (rl + 1) * D_))[k4];
            float4 u2 = ((const float4*)(lu + (rl + 2) * D_))[k4];
            float4 u3 = ((const float4*)(lu + (rl + 3) * D_))[k4];
            a0 = fma4(u0.x, w0, fma4(u0.y, w1, fma4(u0.z, w2, fma4(u0.w, w3, a0))));
            a1 = fma4(u1.x, w0, fma4(u1.y, w1, fma4(u1.z, w2, fma4(u1.w, w3, a1))));
            a2 = fma4(u2.x, w0, fma4(u2.y, w1, fma4(u2.z, w2, fma4(u2.w, w3, a2))));
            a3 = fma4(u3.x, w0, fma4(u3.y, w1, fma4(u3.z, w2, fma4(u3.w, w3, a3))));
        }
        float4 accs[4] = {a0, a1, a2, a3};
#pragma unroll
        for (int r = 0; r < 4; ++r) {
            int row = row0 + rl + r;
            if (row < N_) {
                float4 a = accs[r];
                ushort4 o;
                o.x = f2bf(fmaxf(a.x + bb.x, 0.f));
                o.y = f2bf(fmaxf(a.y + bb.y, 0.f));
                o.z = f2bf(fmaxf(a.z + bb.z, 0.f));
                o.w = f2bf(fmaxf(a.w + bb.w, 0.f));
                ((ushort4*)hout)[(size_t)row * 32 + l] = o;
            }
        }
    }
}

// ---------------------------------------------------------------------------
// 5. Fused mu/logstd GEMM (columns interleaved); z = mu + noise*exp(ls), bf16.
// ---------------------------------------------------------------------------
__global__ __launch_bounds__(256, 2) void k_gemm_z(const unsigned int* __restrict__ gb,
                                                   const float* __restrict__ Wmu,
                                                   const float* __restrict__ bmu,
                                                   const float* __restrict__ Wls,
                                                   const float* __restrict__ bls,
                                                   const float* __restrict__ noise,
                                                   unsigned int* __restrict__ z) {
    __shared__ float lw[D_ * D_];     // 64 KiB (interleaved Wmu|Wls)
    __shared__ float lu[32 * D_];     // 16 KiB
    int tid = threadIdx.x;
    for (int t = tid; t < D_ * 32; t += 256) {
        int k = t >> 5, j2 = t & 31;
        float2 m2 = ((const float2*)Wmu)[k * 32 + j2];
        float2 l2 = ((const float2*)Wls)[k * 32 + j2];
        ((float4*)lw)[t] = make_float4(m2.x, l2.x, m2.y, l2.y);
    }

    int l  = tid & 31;
    int rl = ((tid >> 6) << 3) + (((tid >> 5) & 1) << 2);
    float2 bm = ((const float2*)bmu)[l];
    float2 bl = ((const float2*)bls)[l];
    float4 bb = make_float4(bm.x, bl.x, bm.y, bl.y);

    for (int tile = blockIdx.x; tile * 32 < N_; tile += gridDim.x) {
        int row0 = tile * 32;
        __syncthreads();
#pragma unroll
        for (int i = 0; i < 8; ++i) {
            int t = i * 256 + tid;
            int r = t >> 6, slot = t & 63;
            int gr = row0 + r;
            unsigned int bv = (gr < N_) ? gb[(size_t)gr * 64 + slot] : 0u;
            lu[r * D_ + slot * 2]     = blo(bv);
            lu[r * D_ + slot * 2 + 1] = bhi(bv);
        }
        __syncthreads();
        float4 a0 = {0,0,0,0}, a1 = {0,0,0,0}, a2 = {0,0,0,0}, a3 = {0,0,0,0};
#pragma unroll 4
        for (int k4 = 0; k4 < 32; ++k4) {
            int k = k4 * 4;
            float4 w0 = ((const float4*)(lw + (k + 0) * D_))[l];
            float4 w1 = ((const float4*)(lw + (k + 1) * D_))[l];
            float4 w2 = ((const float4*)(lw + (k + 2) * D_))[l];
            float4 w3 = ((const float4*)(lw + (k + 3) * D_))[l];
            float4 u0 = ((const float4*)(lu + (rl + 0) * D_))[k4];
            float4 u1 = ((const float4*)(lu + (rl + 1) * D_))[k4];
            float4 u2 = ((const float4*)(lu + (rl + 2) * D_))[k4];
            float4 u3 = ((const float4*)(lu + (rl + 3) * D_))[k4];
            a0 = fma4(u0.x, w0, fma4(u0.y, w1, fma4(u0.z, w2, fma4(u0.w, w3, a0))));
            a1 = fma4(u1.x, w0, fma4(u1.y, w1, fma4(u1.z, w2, fma4(u1.w, w3, a1))));
            a2 = fma4(u2.x, w0, fma4(u2.y, w1, fma4(u2.z, w2, fma4(u2.w, w3, a2))));
            a3 = fma4(u3.x, w0, fma4(u3.y, w1, fma4(u3.z, w2, fma4(u3.w, w3, a3))));
        }
        float4 accs[4] = {a0, a1, a2, a3};
#pragma unroll
        for (int r = 0; r < 4; ++r) {
            int row = row0 + rl + r;
            if (row < N_) {
                float4 a = accs[r];
                float2 n2 = ((const float2*)noise)[(size_t)row * 32 + l];
                float z0 = (a.x + bb.x) + n2.x * expf(a.y + bb.y);
                float z1 = (a.z + bb.z) + n2.y * expf(a.w + bb.w);
                z[(size_t)row * 32 + l] = pack2(z0, z1);
            }
        }
    }
}

// ---------------------------------------------------------------------------
// 6. Decoder: logits[e] = dot(z[src], z[dst]) over 64 bf16.
//    8 lanes x uint4 per row; 4 edges batched per group -> 8 loads in flight;
//    lane 0 writes a coalesced float4 of 4 logits.
// ---------------------------------------------------------------------------
__global__ __launch_bounds__(256) void k_decode(const int* __restrict__ src,
                                                const int* __restrict__ dst,
                                                const unsigned int* __restrict__ z,
                                                float* __restrict__ out) {
    int l = threadIdx.x & 7;
    int e0 = blockIdx.x * 128 + ((threadIdx.x >> 3) << 2);   // E_ % 128 == 0
    int s0 = src[e0],     d0 = dst[e0];
    int s1 = src[e0 + 1], d1 = dst[e0 + 1];
    int s2 = src[e0 + 2], d2 = dst[e0 + 2];
    int s3 = src[e0 + 3], d3 = dst[e0 + 3];
    const uint4* Z = (const uint4*)z;
    uint4 za0 = Z[(size_t)s0 * 8 + l], zb0 = Z[(size_t)d0 * 8 + l];
    uint4 za1 = Z[(size_t)s1 * 8 + l], zb1 = Z[(size_t)d1 * 8 + l];
    uint4 za2 = Z[(size_t)s2 * 8 + l], zb2 = Z[(size_t)d2 * 8 + l];
    uint4 za3 = Z[(size_t)s3 * 8 + l], zb3 = Z[(size_t)d3 * 8 + l];
    float p0 = blo(za0.x) * blo(zb0.x) + bhi(za0.x) * bhi(zb0.x)
             + blo(za0.y) * blo(zb0.y) + bhi(za0.y) * bhi(zb0.y)
             + blo(za0.z) * blo(zb0.z) + bhi(za0.z) * bhi(zb0.z)
             + blo(za0.w) * blo(zb0.w) + bhi(za0.w) * bhi(zb0.w);
    float p1 = blo(za1.x) * blo(zb1.x) + bhi(za1.x) * bhi(zb1.x)
             + blo(za1.y) * blo(zb1.y) + bhi(za1.y) * bhi(zb1.y)
             + blo(za1.z) * blo(zb1.z) + bhi(za1.z) * bhi(zb1.z)
             + blo(za1.w) * blo(zb1.w) + bhi(za1.w) * bhi(zb1.w);
    float p2 = blo(za2.x) * blo(zb2.x) + bhi(za2.x) * bhi(zb2.x)
             + blo(za2.y) * blo(zb2.y) + bhi(za2.y) * bhi(zb2.y)
             + blo(za2.z) * blo(zb2.z) + bhi(za2.z) * bhi(zb2.z)
             + blo(za2.w) * blo(zb2.w) + bhi(za2.w) * bhi(zb2.w);
    float p3 = blo(za3.x) * blo(zb3.x) + bhi(za3.x) * bhi(zb3.x)
             + blo(za3.y) * blo(zb3.y) + bhi(za3.y) * bhi(zb3.y)
             + blo(za3.z) * blo(zb3.z) + bhi(za3.z) * bhi(zb3.z)
             + blo(za3.w) * blo(zb3.w) + bhi(za3.w) * bhi(zb3.w);
#pragma unroll
    for (int o = 4; o; o >>= 1) {
        p0 += __shfl_xor(p0, o);
        p1 += __shfl_xor(p1, o);
        p2 += __shfl_xor(p2, o);
        p3 += __shfl_xor(p3, o);
    }
    if (l == 0) ((float4*)out)[e0 >> 2] = make_float4(p0, p1, p2, p3);
}

// ---------------------------------------------------------------------------
extern "C" void kernel_launch(void* const* d_in, const int* in_sizes, int n_in,
                              void* d_out, int out_size, void* d_ws, size_t ws_size,
                              hipStream_t stream) {
    const int*   fi    = (const int*)d_in[0];
    const float* fw    = (const float*)d_in[2];
    const int*   ei    = (const int*)d_in[3];
    const float* noise = (const float*)d_in[4];
    const float* emb   = (const float*)d_in[5];
    const float* W1    = (const float*)d_in[6];
    const float* b1    = (const float*)d_in[7];
    const float* Wmu   = (const float*)d_in[8];
    const float* bmu   = (const float*)d_in[9];
    const float* Wls   = (const float*)d_in[10];
    const float* bls   = (const float*)d_in[11];
    float* out = (float*)d_out;

    const int* src = ei;
    const int* dst = ei + E_;

    // Workspace layout (4-byte units). The 25.6MB alias region serves, in
    // non-overlapping lifetime order: emb_bf (cvt->embed), binned (bin->fill2),
    // agg bf16 (gather->gemm; first 12.8MB).
    float*        ws        = (float*)d_ws;
    unsigned int* aggb      = (unsigned int*)ws;                     // N*64 u32 = 12.8MB
    unsigned int* emb_bf    = (unsigned int*)ws;                     // V*64 u32 = 25.6MB
    unsigned int* binned    = (unsigned int*)ws;                     // E u32 = 6.4MB
    unsigned int* x         = (unsigned int*)ws + (size_t)V_ * 64;   // N*64 u32
    unsigned int* h         = x + (size_t)N_ * 64;                   // N*64 u32
    unsigned int* z         = h + (size_t)N_ * 64;                   // N*32 u32
    float*        disq      = (float*)(z + (size_t)N_ * 32);         // N
    float*        dinv      = disq + N_;                             // N
    int*          row_start = (int*)(dinv + N_);                     // N+1
    int*          sorted_src= row_start + (N_ + 1);                  // E
    int*          bin_total = sorted_src + E_;                       // 256
    int*          coarse_start  = bin_total + 256;                   // NBIN+1
    int*          coarse_cursor = coarse_start + 256;                // NBIN+1

    hipMemsetAsync(bin_total, 0, 256 * sizeof(int), stream);

    k_cvt    <<<(V_ * D_ / 8 + 255) / 256, 256, 0, stream>>>(emb, emb_bf);
    k_embed  <<<(N_ + 7) / 8,           256, 0, stream>>>(fi, fw, emb_bf, x);
    k_bhist  <<<(E_ + EPB_ - 1) / EPB_, 256, 0, stream>>>(dst, bin_total);
    k_scan196<<<1,                      256, 0, stream>>>(bin_total, coarse_start,
                                                          coarse_cursor, row_start);
    k_bin    <<<(E_ + EPB_ - 1) / EPB_, 256, 0, stream>>>(src, dst, coarse_cursor, binned);
    k_node   <<<NBIN_,                  256, 0, stream>>>(binned, coarse_start,
                                                          disq, dinv, row_start);
    k_fill2  <<<NBIN_,                  256, 0, stream>>>(binned, coarse_start,
                                                          row_start, sorted_src);

    // GCN layer 1
    k_gather   <<<N_ / 4, 256, 0, stream>>>(row_start, sorted_src, disq, dinv, x, aggb);
    k_gemm_relu<<<512,    256, 0, stream>>>(aggb, W1, b1, (unsigned short*)h);

    // GCN layers 2+3 (one gather of h, fused mu/ls GEMM)
    k_gather <<<N_ / 4,   256, 0, stream>>>(row_start, sorted_src, disq, dinv, h, aggb);
    k_gemm_z <<<512,      256, 0, stream>>>(aggb, Wmu, bmu, Wls, bls, noise, z);

    // Decoder
    k_decode <<<E_ / 128, 256, 0, stream>>>(src, dst, z, out);
}